// Round 10
// baseline (314.566 us; speedup 1.0000x reference)
//
#include <hip/hip_runtime.h>
#include <hip/hip_fp16.h>

// Problem constants (fixed by the reference setup)
#define N_NODES 50000
#define IN_DIM 256
#define OUT_DIM 128
#define NNZ 800000          // nnz for feat, adj1, adj2 each
#define N_ADJ_TOT (2 * NNZ)          // 1.6M sorted adj entries (feat NOT sorted)
#define SCAN_N (2 * N_NODES)         // 100000 row counters (adj1 | adj2)
#define SCAN_BLOCKS ((SCAN_N + 255) / 256)   // 391
#define NPART 8                      // one row-partition per XCD
#define PART_W (N_NODES / NPART)     // 6250 rows per partition

// Level-1 per-partition bucket capacity (adj only).
// Expected 1.6M/8 = 200000, sigma ~418; 208128 = +19.4 sigma, multiple of 256.
#define BCAP 208128

// Level-2 sub-buckets: 64 per partition, 98 rows each.
// Expected 1.6M*98/50000 = 3136, sigma ~56; 4096 = +17 sigma = 8*512.
#define NSUB 64
#define SUBW 98
#define SUBCAP 4096
#define ENT_B 4096
#define BBLK_B ((BCAP + ENT_B - 1) / ENT_B)   // 51 blocks per partition

// adj phase: TWO dispatches (rel0 raw-acc, rel1 acc+relu); 32-dim slices
// (64 B/row-slice) -> per-XCD working set 3.2 MB, L2-resident (round-9: works).
#define ADJ_SL 4
#define ADJ_RC ((N_NODES + 63) / 64)  // 782 row-chunks of 64 rows

// Native clang vector types.
typedef float vf4 __attribute__((ext_vector_type(4)));
typedef float f32x4a __attribute__((ext_vector_type(4)));
typedef _Float16 f16x8 __attribute__((ext_vector_type(8)));

// Packed entry: [col:16 | fp16(val):16].  adj cols < 50000 < 65536.
static __device__ __forceinline__ unsigned pack_cv(int c, float v) {
    return ((unsigned)c << 16) | (unsigned)__half_as_ushort(__float2half(v));
}
static __device__ __forceinline__ int   upk_c(unsigned pk) { return (int)(pk >> 16); }
static __device__ __forceinline__ float upk_v(unsigned pk) {
    return __half2float(__ushort_as_half((unsigned short)(pk & 0xffffu)));
}
static __device__ __forceinline__ float h2f(unsigned short h) {
    return __half2float(__ushort_as_half(h));
}

// -----------------------------------------------------------------------------
// FEAT PHASE (no sort): densify X (atomicAdd handles duplicate (r,c) edges,
// matching segment_sum), then X @ [W1|W2] via MFMA f16 (fp32 accumulate).
// -----------------------------------------------------------------------------
__global__ void densify_kernel(const int* __restrict__ fr,
                               const int* __restrict__ fc,
                               const float* __restrict__ fv,
                               float* __restrict__ X) {
    int e = blockIdx.x * 256 + threadIdx.x;       // NNZ = 3125*256 exact
    int r = __builtin_nontemporal_load(&fr[e]);
    int c = __builtin_nontemporal_load(&fc[e]);
    float v = __builtin_nontemporal_load(&fv[e]);
    atomicAdd(&X[(size_t)r * IN_DIM + c], v);
}

// Pack Wc = [W1|W2] (256x256 fp32) into MFMA B-fragment layout, fp16.
// Bfrag[tk=ct*8+kk][lane] : lane l holds col = ct*16+(l&15),
// k = kk*32 + (l>>4)*8 + i (i=0..7). Same k-order as the A-fragment build in
// feat_mfma_kernel, so any k-permutation error cancels in the dot product.
__global__ void bprep_kernel(const float* __restrict__ W1,
                             const float* __restrict__ W2,
                             f16x8* __restrict__ Bfrag) {
    int idx = blockIdx.x * 256 + threadIdx.x;     // 32 blocks -> 8192
    int tk = idx >> 6, l = idx & 63;              // tk in [0,128)
    int ct = tk >> 3, kk = tk & 7;
    int col = ct * 16 + (l & 15);
    int kb = kk * 32 + ((l >> 4) << 3);
    f16x8 b;
#pragma unroll
    for (int i = 0; i < 8; ++i) {
        int k = kb + i;
        float w = (col < OUT_DIM) ? W1[k * OUT_DIM + col]
                                  : W2[k * OUT_DIM + (col - OUT_DIM)];
        b[i] = (_Float16)w;
    }
    Bfrag[tk * 64 + l] = b;
}

// GEMM: xw[r, 0:256] = X[r, :] @ Wc. Block = 16 rows x 256 cols, 4 waves;
// wave w does col-tiles 4w..4w+3 (cols 64w..64w+63). 8 K-steps of
// mfma_f32_16x16x32_f16. Output written directly in the 32-dim-slice fp16
// layout the adj passes consume. C/D map (m89-verified): col=lane&15,
// row=(lane>>4)*4+j.
__global__ __launch_bounds__(256) void feat_mfma_kernel(
        const float* __restrict__ X,
        const f16x8* __restrict__ Bfrag,
        __half* __restrict__ xw1h,
        __half* __restrict__ xw2h) {
    int r0 = blockIdx.x * 16;                     // 3125 blocks, 50000 = 3125*16
    int w = threadIdx.x >> 6, l = threadIdx.x & 63;
    f32x4a acc0 = {0.f,0.f,0.f,0.f}, acc1 = {0.f,0.f,0.f,0.f};
    f32x4a acc2 = {0.f,0.f,0.f,0.f}, acc3 = {0.f,0.f,0.f,0.f};
    int row = r0 + (l & 15);
    const float* ap = X + (size_t)row * IN_DIM + ((l >> 4) << 3);
#pragma unroll
    for (int kk = 0; kk < 8; ++kk) {
        const float4* a4 = (const float4*)(ap + kk * 32);
        float4 x0 = a4[0];
        float4 x1 = a4[1];
        f16x8 a;
        a[0] = (_Float16)x0.x; a[1] = (_Float16)x0.y;
        a[2] = (_Float16)x0.z; a[3] = (_Float16)x0.w;
        a[4] = (_Float16)x1.x; a[5] = (_Float16)x1.y;
        a[6] = (_Float16)x1.z; a[7] = (_Float16)x1.w;
        f16x8 b0 = Bfrag[((4 * w + 0) * 8 + kk) * 64 + l];
        f16x8 b1 = Bfrag[((4 * w + 1) * 8 + kk) * 64 + l];
        f16x8 b2 = Bfrag[((4 * w + 2) * 8 + kk) * 64 + l];
        f16x8 b3 = Bfrag[((4 * w + 3) * 8 + kk) * 64 + l];
        acc0 = __builtin_amdgcn_mfma_f32_16x16x32_f16(a, b0, acc0, 0, 0, 0);
        acc1 = __builtin_amdgcn_mfma_f32_16x16x32_f16(a, b1, acc1, 0, 0, 0);
        acc2 = __builtin_amdgcn_mfma_f32_16x16x32_f16(a, b2, acc2, 0, 0, 0);
        acc3 = __builtin_amdgcn_mfma_f32_16x16x32_f16(a, b3, acc3, 0, 0, 0);
    }
#pragma unroll
    for (int ct = 0; ct < 4; ++ct) {
        f32x4a acc = (ct == 0) ? acc0 : (ct == 1) ? acc1 : (ct == 2) ? acc2 : acc3;
        int col = (4 * w + ct) * 16 + (l & 15);
        int dim = col & (OUT_DIM - 1);
        __half* base = (col < OUT_DIM) ? xw1h : xw2h;
        int slice = dim >> 5, within = dim & 31;
        size_t sb = (size_t)slice * N_NODES * 32 + within;
#pragma unroll
        for (int j = 0; j < 4; ++j) {
            int rr = r0 + ((l >> 4) << 2) + j;
            base[sb + (size_t)rr * 32] = __float2half(acc[j]);
        }
    }
}

// -----------------------------------------------------------------------------
// CSR build (ADJ ONLY now — 1.6M entries, was 2.4M), round-2 pipeline.
// -----------------------------------------------------------------------------
__global__ void bucket_kernel(const int* __restrict__ a1r, const int* __restrict__ a1c,
                              const float* __restrict__ a1v,
                              const int* __restrict__ a2r, const int* __restrict__ a2c,
                              const float* __restrict__ a2v,
                              int* __restrict__ bcur,
                              unsigned* __restrict__ gpack,
                              unsigned short* __restrict__ gmeta) {
    __shared__ int cnt8[8];
    __shared__ int offc[8];
    __shared__ int gbase[8];
    __shared__ unsigned spk[512];
    __shared__ unsigned short smeta[512];
    int t = threadIdx.x;
    if (t < 8) cnt8[t] = 0;
    __syncthreads();

    int e = blockIdx.x * 256 + t;        // NNZ = 3125 * 256, no tail
    int r[2]; unsigned pk[2]; int loc[2]; int pb[2];
    r[0] = __builtin_nontemporal_load(&a1r[e]);
    pk[0] = pack_cv(__builtin_nontemporal_load(&a1c[e]),
                    __builtin_nontemporal_load(&a1v[e]));
    r[1] = __builtin_nontemporal_load(&a2r[e]);
    pk[1] = pack_cv(__builtin_nontemporal_load(&a2c[e]),
                    __builtin_nontemporal_load(&a2v[e]));
#pragma unroll
    for (int s = 0; s < 2; ++s) {
        pb[s] = r[s] / PART_W;
        loc[s] = atomicAdd(&cnt8[pb[s]], 1);
    }
    __syncthreads();
    if (t < 8) gbase[t] = atomicAdd(&bcur[t], cnt8[t]);
    if (t == 0) {
        int acc = 0;
#pragma unroll
        for (int q = 0; q < 8; ++q) { offc[q] = acc; acc += cnt8[q]; }
    }
    __syncthreads();
#pragma unroll
    for (int s = 0; s < 2; ++s) {
        int pos = offc[pb[s]] + loc[s];
        spk[pos] = pk[s];
        smeta[pos] = (unsigned short)((s << 13) | (r[s] - pb[s] * PART_W));
    }
    __syncthreads();
#pragma unroll
    for (int k = 0; k < 2; ++k) {
        int i = t + k * 256;
        int q = 0;
#pragma unroll
        for (int b = 1; b < 8; ++b) q += (i >= offc[b]);
        int g = q * BCAP + gbase[q] + (i - offc[q]);
        gpack[g] = spk[i];
        gmeta[g] = smeta[i];
    }
}

// Pass B: partition bucket -> 64 sub-buckets (98-row ranges). blockIdx&7 = p.
__global__ void subbucket_kernel(const unsigned* __restrict__ gpack1,
                                 const unsigned short* __restrict__ gmeta1,
                                 const int* __restrict__ bcur,
                                 int* __restrict__ subcur,
                                 unsigned* __restrict__ gpack2,
                                 unsigned short* __restrict__ gmeta2) {
    int p = blockIdx.x & (NPART - 1);
    int chunk = blockIdx.x >> 3;
    int base = chunk * ENT_B;
    int n = bcur[p];
    int cnt = n - base;
    if (cnt <= 0) return;                // uniform across block
    if (cnt > ENT_B) cnt = ENT_B;
    __shared__ int c64[NSUB], off[NSUB], gb[NSUB];
    __shared__ unsigned spk[ENT_B];
    __shared__ unsigned short smt[ENT_B];
    int t = threadIdx.x;
    if (t < NSUB) c64[t] = 0;
    __syncthreads();
    unsigned pk[16]; unsigned short mt[16]; int loc[16]; int sb[16];
#pragma unroll
    for (int k = 0; k < 16; ++k) {
        int i = t + k * 256;
        if (i < cnt) {
            pk[k] = gpack1[p * BCAP + base + i];
            mt[k] = gmeta1[p * BCAP + base + i];
            sb[k] = (int)(mt[k] & 8191u) / SUBW;
            loc[k] = atomicAdd(&c64[sb[k]], 1);
        } else sb[k] = -1;
    }
    __syncthreads();
    if (t == 0) {
        int a = 0;
#pragma unroll
        for (int q = 0; q < NSUB; ++q) { off[q] = a; a += c64[q]; }
    }
    __syncthreads();
    if (t < NSUB && c64[t] > 0) gb[t] = atomicAdd(&subcur[p * NSUB + t], c64[t]);
    __syncthreads();
#pragma unroll
    for (int k = 0; k < 16; ++k) {
        if (sb[k] >= 0) {
            int pos = off[sb[k]] + loc[k];
            spk[pos] = pk[k];
            smt[pos] = mt[k];
        }
    }
    __syncthreads();
    for (int i = t; i < cnt; i += 256) {
        unsigned short m = smt[i];
        int s2 = (int)(m & 8191u) / SUBW;
        int g = (p * NSUB + s2) * SUBCAP + gb[s2] + (i - off[s2]);
        gpack2[g] = spk[i];
        gmeta2[g] = m;
    }
}

// Pass C1: per-sub-bucket histogram -> cnt (plain stores, covers all of cnt).
__global__ __launch_bounds__(512) void subhist_kernel(
        const unsigned short* __restrict__ gmeta2,
        const int* __restrict__ subcur,
        int* __restrict__ cnt) {
    int p = blockIdx.x & (NPART - 1);
    int sub = blockIdx.x >> 3;
    int n = subcur[p * NSUB + sub];
    __shared__ int h[512];
    int t = threadIdx.x;
    h[t] = 0;
    __syncthreads();
    long base = (long)(p * NSUB + sub) * SUBCAP;
    for (int i = t; i < n; i += 512) {
        unsigned short m = gmeta2[base + i];
        int key = (int)(m >> 13) * SUBW + ((int)(m & 8191u) - sub * SUBW);
        atomicAdd(&h[key], 1);
    }
    __syncthreads();
    if (t < 2 * SUBW) {
        int s = t / SUBW, d = t - s * SUBW;
        int rl = sub * SUBW + d;
        if (rl < PART_W) cnt[s * N_NODES + p * PART_W + rl] = h[t];
    }
}

__global__ void scan_block_kernel(const int* __restrict__ cnt,
                                  int* __restrict__ starts,
                                  int* __restrict__ bsum) {
    __shared__ int tmp[256];
    int g = blockIdx.x * 256 + threadIdx.x;
    int v = (g < SCAN_N) ? cnt[g] : 0;
    tmp[threadIdx.x] = v;
    __syncthreads();
    for (int off = 1; off < 256; off <<= 1) {
        int t = (threadIdx.x >= off) ? tmp[threadIdx.x - off] : 0;
        __syncthreads();
        tmp[threadIdx.x] += t;
        __syncthreads();
    }
    int incl = tmp[threadIdx.x];
    if (g < SCAN_N) starts[g] = incl - v;          // exclusive
    if (threadIdx.x == 255) bsum[blockIdx.x] = incl;
}

__global__ void scan_bsum_kernel(int* __restrict__ bsum, int nb) {
    __shared__ int tmp[1024];
    int t = threadIdx.x;
    int v = (t < nb) ? bsum[t] : 0;
    tmp[t] = v;
    __syncthreads();
    for (int off = 1; off < 1024; off <<= 1) {
        int x = (t >= off) ? tmp[t - off] : 0;
        __syncthreads();
        tmp[t] += x;
        __syncthreads();
    }
    if (t < nb) bsum[t] = tmp[t] - v;              // exclusive block offsets
}

__global__ void scan_add_kernel(int* __restrict__ starts,
                                const int* __restrict__ bsum) {
    int g = blockIdx.x * 256 + threadIdx.x;
    if (g < SCAN_N) starts[g] += bsum[blockIdx.x];
}

// Pass C2: LDS counting sort of one sub-bucket -> TWO contiguous spack ranges.
__global__ __launch_bounds__(512) void sort_write_kernel(
        const unsigned* __restrict__ gpack2,
        const unsigned short* __restrict__ gmeta2,
        const int* __restrict__ subcur,
        const int* __restrict__ starts,
        unsigned* __restrict__ spack) {
    int p = blockIdx.x & (NPART - 1);
    int sub = blockIdx.x >> 3;
    int n = subcur[p * NSUB + sub];
    __shared__ int h[512];
    __shared__ int e[512];
    __shared__ int cur[512];
    __shared__ unsigned sorted[SUBCAP];
    int t = threadIdx.x;
    h[t] = 0;
    __syncthreads();
    long base = (long)(p * NSUB + sub) * SUBCAP;
    unsigned pk[8]; short ky[8];
#pragma unroll
    for (int k = 0; k < 8; ++k) {            // SUBCAP = 8*512 exactly
        int i = t + k * 512;
        if (i < n) {
            pk[k] = gpack2[base + i];
            unsigned short m = gmeta2[base + i];
            int key = (int)(m >> 13) * SUBW + ((int)(m & 8191u) - sub * SUBW);
            ky[k] = (short)key;
            atomicAdd(&h[key], 1);
        } else ky[k] = -1;
    }
    __syncthreads();
    e[t] = h[t];
    __syncthreads();
    for (int off = 1; off < 512; off <<= 1) {
        int v = (t >= off) ? e[t - off] : 0;
        __syncthreads();
        e[t] += v;
        __syncthreads();
    }
    int excl = e[t] - h[t];
    __syncthreads();
    e[t] = excl;
    cur[t] = excl;
    __syncthreads();
#pragma unroll
    for (int k = 0; k < 8; ++k) {
        if (ky[k] >= 0) {
            int pos = atomicAdd(&cur[ky[k]], 1);
            sorted[pos] = pk[k];
        }
    }
    __syncthreads();
    int s1 = e[SUBW];                         // local start of adj2 entries
    int rb = p * PART_W + sub * SUBW;
    int gb0 = starts[rb];
    int gb1 = starts[N_NODES + rb];
#pragma unroll
    for (int k = 0; k < 8; ++k) {
        int i = t + k * 512;
        if (i < n) {
            unsigned v = sorted[i];
            int dst = (i < s1) ? (gb0 + i) : (gb1 + (i - s1));
            spack[dst] = v;
        }
    }
}

// -----------------------------------------------------------------------------
// Phase 2 (unchanged from round 9): rel-split, 32-dim slices, full-line gathers.
// adj1 rows at starts[0..50K), adj2 at starts[50K..100K).
// -----------------------------------------------------------------------------
__global__ __launch_bounds__(512) void adj_pass_rel0(
        const int* __restrict__ starts,
        const unsigned* __restrict__ spack,
        const ushort4* __restrict__ xws,
        vf4* __restrict__ out) {
    int s  = blockIdx.x & (ADJ_SL - 1);
    int rc = blockIdx.x >> 2;
    int g  = threadIdx.x >> 3;          // 64 row-groups per block
    int q  = threadIdx.x & 7;
    int r  = rc * 64 + g;
    bool valid = (r < N_NODES);
    vf4 acc = {0.f, 0.f, 0.f, 0.f};
    const ushort4* __restrict__ sl = xws + (size_t)s * (N_NODES * 8);
    size_t oidx = (size_t)r * 32 + s * 8 + q;

    int st = 0, en = 0;
    if (valid) {
        st = starts[r];
        en = starts[r + 1];             // starts[50000] = adj2 base, safe
    }
    for (int base = st; base < en; base += 16) {
        int m = en - base;
        unsigned pk0 = (q < m)     ? spack[base + q]     : 0u;
        unsigned pk1 = (8 + q < m) ? spack[base + 8 + q] : 0u;
        {
            unsigned pp[8]; ushort4 xx[8];
#pragma unroll
            for (int k = 0; k < 8; ++k) pp[k] = __shfl(pk0, k, 8);
#pragma unroll
            for (int k = 0; k < 8; ++k) xx[k] = sl[upk_c(pp[k]) * 8 + q];
#pragma unroll
            for (int k = 0; k < 8; ++k) {
                float v = upk_v(pp[k]);
                acc.x += v * h2f(xx[k].x); acc.y += v * h2f(xx[k].y);
                acc.z += v * h2f(xx[k].z); acc.w += v * h2f(xx[k].w);
            }
        }
        if (m <= 8) continue;
        {
            unsigned pp[8]; ushort4 xx[8];
#pragma unroll
            for (int k = 0; k < 8; ++k) pp[k] = __shfl(pk1, k, 8);
#pragma unroll
            for (int k = 0; k < 8; ++k) xx[k] = sl[upk_c(pp[k]) * 8 + q];
#pragma unroll
            for (int k = 0; k < 8; ++k) {
                float v = upk_v(pp[k]);
                acc.x += v * h2f(xx[k].x); acc.y += v * h2f(xx[k].y);
                acc.z += v * h2f(xx[k].z); acc.w += v * h2f(xx[k].w);
            }
        }
    }
    if (valid) __builtin_nontemporal_store(acc, &out[oidx]);   // raw partial sum
}

__global__ __launch_bounds__(512) void adj_pass_rel1(
        const int* __restrict__ starts,
        const unsigned* __restrict__ spack,
        const ushort4* __restrict__ xws,
        vf4* __restrict__ out) {
    int s  = blockIdx.x & (ADJ_SL - 1);
    int rc = blockIdx.x >> 2;
    int g  = threadIdx.x >> 3;
    int q  = threadIdx.x & 7;
    int r  = rc * 64 + g;
    bool valid = (r < N_NODES);
    vf4 acc = {0.f, 0.f, 0.f, 0.f};
    const ushort4* __restrict__ sl = xws + (size_t)s * (N_NODES * 8);
    size_t oidx = (size_t)r * 32 + s * 8 + q;

    int st = 0, en = 0;
    if (valid) {
        st = starts[N_NODES + r];
        en = (r == N_NODES - 1) ? N_ADJ_TOT : starts[N_NODES + r + 1];
    }
    vf4 prev = {0.f, 0.f, 0.f, 0.f};
    if (valid) prev = __builtin_nontemporal_load(&out[oidx]);  // early, overlaps loop

    for (int base = st; base < en; base += 16) {
        int m = en - base;
        unsigned pk0 = (q < m)     ? spack[base + q]     : 0u;
        unsigned pk1 = (8 + q < m) ? spack[base + 8 + q] : 0u;
        {
            unsigned pp[8]; ushort4 xx[8];
#pragma unroll
            for (int k = 0; k < 8; ++k) pp[k] = __shfl(pk0, k, 8);
#pragma unroll
            for (int k = 0; k < 8; ++k) xx[k] = sl[upk_c(pp[k]) * 8 + q];
#pragma unroll
            for (int k = 0; k < 8; ++k) {
                float v = upk_v(pp[k]);
                acc.x += v * h2f(xx[k].x); acc.y += v * h2f(xx[k].y);
                acc.z += v * h2f(xx[k].z); acc.w += v * h2f(xx[k].w);
            }
        }
        if (m <= 8) continue;
        {
            unsigned pp[8]; ushort4 xx[8];
#pragma unroll
            for (int k = 0; k < 8; ++k) pp[k] = __shfl(pk1, k, 8);
#pragma unroll
            for (int k = 0; k < 8; ++k) xx[k] = sl[upk_c(pp[k]) * 8 + q];
#pragma unroll
            for (int k = 0; k < 8; ++k) {
                float v = upk_v(pp[k]);
                acc.x += v * h2f(xx[k].x); acc.y += v * h2f(xx[k].y);
                acc.z += v * h2f(xx[k].z); acc.w += v * h2f(xx[k].w);
            }
        }
    }
    if (valid) {
        vf4 res;
        res.x = fmaxf(acc.x + prev.x, 0.f);
        res.y = fmaxf(acc.y + prev.y, 0.f);
        res.z = fmaxf(acc.z + prev.z, 0.f);
        res.w = fmaxf(acc.w + prev.w, 0.f);
        __builtin_nontemporal_store(res, &out[oidx]);
    }
}

extern "C" void kernel_launch(void* const* d_in, const int* in_sizes, int n_in,
                              void* d_out, int out_size, void* d_ws, size_t ws_size,
                              hipStream_t stream) {
    const int*   feat_row  = (const int*)  d_in[0];
    const int*   feat_col  = (const int*)  d_in[1];
    const float* feat_vals = (const float*)d_in[2];
    const int*   adj1_row  = (const int*)  d_in[3];
    const int*   adj1_col  = (const int*)  d_in[4];
    const float* adj1_vals = (const float*)d_in[5];
    const int*   adj2_row  = (const int*)  d_in[6];
    const int*   adj2_col  = (const int*)  d_in[7];
    const float* adj2_vals = (const float*)d_in[8];
    const float* W1        = (const float*)d_in[9];
    const float* W2        = (const float*)d_in[10];

    // Workspace layout (~84 MB). Bucket region (~22.6 MB) is dead after
    // sort_write; xw1/xw2 (25.6 MB) alias it (GEMM runs after sort_write).
    char* ws = (char*)d_ws;
    unsigned* spack = (unsigned*)ws;            ws += (size_t)N_ADJ_TOT * 4;          // 6.4 MB
    int*      cnt   = (int*)ws;                 ws += (size_t)SCAN_N * 4;             // 400 KB
    int*      starts= (int*)ws;                 ws += (size_t)SCAN_N * 4;             // 400 KB
    int*      bsum  = (int*)ws;                 ws += 1024 * 4;
    int*      bcur  = (int*)ws;                 ws += 16 * 4;                         // 8 used
    int*      subcur= (int*)ws;                 ws += (size_t)NPART * NSUB * 4;       // 2 KB
    float*    X     = (float*)ws;               ws += (size_t)N_NODES * IN_DIM * 4;   // 51.2 MB
    f16x8*    Bfrag = (f16x8*)ws;               ws += (size_t)128 * 64 * 16;          // 128 KB
    char*     bkt   = ws;                       // bucket region (aliased by xw)
    unsigned* gpack1 = (unsigned*)bkt;
    unsigned short* gmeta1 = (unsigned short*)(bkt + (size_t)NPART * BCAP * 4);
    unsigned* gpack2 = (unsigned*)(bkt + (size_t)NPART * BCAP * 6);
    unsigned short* gmeta2 = (unsigned short*)(bkt + (size_t)NPART * BCAP * 6
                                                  + (size_t)NPART * NSUB * SUBCAP * 4);
    __half*   xw1h  = (__half*)bkt;                                      // alias (after C2)
    __half*   xw2h  = (__half*)(bkt + (size_t)N_NODES * OUT_DIM * 2);    // alias

    // Zero bucket cursors (bcur+subcur adjacent) and the dense X.
    (void)hipMemsetAsync(bcur, 0, (16 + NPART * NSUB) * sizeof(int), stream);
    (void)hipMemsetAsync(X, 0, (size_t)N_NODES * IN_DIM * sizeof(float), stream);

    const int block = 256;

    // FEAT densify + B-fragment prep (independent of the sort).
    densify_kernel<<<NNZ / block, block, 0, stream>>>(feat_row, feat_col, feat_vals, X);
    bprep_kernel<<<32, block, 0, stream>>>(W1, W2, Bfrag);

    // ADJ CSR build (1.6M entries).
    bucket_kernel<<<NNZ / block, block, 0, stream>>>(
        adj1_row, adj1_col, adj1_vals,
        adj2_row, adj2_col, adj2_vals,
        bcur, gpack1, gmeta1);
    subbucket_kernel<<<NPART * BBLK_B, block, 0, stream>>>(
        gpack1, gmeta1, bcur, subcur, gpack2, gmeta2);
    subhist_kernel<<<NPART * NSUB, 512, 0, stream>>>(gmeta2, subcur, cnt);
    scan_block_kernel<<<SCAN_BLOCKS, 256, 0, stream>>>(cnt, starts, bsum);
    scan_bsum_kernel<<<1, 1024, 0, stream>>>(bsum, SCAN_BLOCKS);
    scan_add_kernel<<<SCAN_BLOCKS, 256, 0, stream>>>(starts, bsum);
    sort_write_kernel<<<NPART * NSUB, 512, 0, stream>>>(
        gpack2, gmeta2, subcur, starts, spack);

    // FEAT GEMM (after sort_write: xw aliases the bucket region).
    feat_mfma_kernel<<<N_NODES / 16, 256, 0, stream>>>(X, Bfrag, xw1h, xw2h);

    // ADJ passes (rel-split, 32-dim slices).
    adj_pass_rel0<<<ADJ_SL * ADJ_RC, 512, 0, stream>>>(
        starts, spack, (const ushort4*)xw1h, (vf4*)d_out);
    adj_pass_rel1<<<ADJ_SL * ADJ_RC, 512, 0, stream>>>(
        starts, spack, (const ushort4*)xw2h, (vf4*)d_out);
}

// Round 11
// 259.464 us; speedup vs baseline: 1.2124x; 1.2124x over previous
//
#include <hip/hip_runtime.h>
#include <hip/hip_fp16.h>

// Problem constants (fixed by the reference setup)
#define N_NODES 50000
#define IN_DIM 256
#define OUT_DIM 128
#define NNZ 800000          // nnz for feat, adj1, adj2 each
#define SCAN_N (3 * N_NODES)        // 150000 row pointers (feat | adj1 | adj2)
#define TOTAL_NNZ (3 * NNZ)         // 2.4M sorted entries
#define NPART 8                      // one row-partition per XCD
#define PART_W (N_NODES / NPART)     // 6250 rows per partition

// Level-1 per-partition bucket capacity.
#define BCAP 310016

// Level-2 sub-buckets: 64 per partition, 98 rows each.
#define NSUB 64
#define SUBW 98
#define SUBCAP 6144
#define ENT_B 4096
#define BBLK_B ((BCAP + ENT_B - 1) / ENT_B)   // 76 blocks per partition

// adj phase: TWO dispatches (rel0 raw-acc, rel1 acc+relu); 32-dim slices
// (64 B/row-slice) -> per-XCD working set 3.2 MB, L2-resident (round-9: works).
#define ADJ_SL 4
#define ADJ_RC ((N_NODES + 63) / 64)  // 782 row-chunks of 64 rows

// Native clang vector types.
typedef float vf4 __attribute__((ext_vector_type(4)));

// Packed entry: [col:16 | fp16(val):16].  adj cols < 50000 < 65536, feat cols < 256.
static __device__ __forceinline__ unsigned pack_cv(int c, float v) {
    return ((unsigned)c << 16) | (unsigned)__half_as_ushort(__float2half(v));
}
static __device__ __forceinline__ int   upk_c(unsigned pk) { return (int)(pk >> 16); }
static __device__ __forceinline__ float upk_v(unsigned pk) {
    return __half2float(__ushort_as_half((unsigned short)(pk & 0xffffu)));
}
static __device__ __forceinline__ float h2f(unsigned short h) {
    return __half2float(__ushort_as_half(h));
}

// -----------------------------------------------------------------------------
// CSR build, now THREE kernels (was seven):
//   A (bucket_kernel):    read every edge once, LDS-group by partition (row/6250).
//   B (subbucket_kernel): partition bucket -> 64 sub-buckets (98-row ranges).
//   C (sort_write_kernel): per-sub-bucket LDS counting sort; the block RESERVES
//     its output ranges via 3 per-segment atomic cursors and emits starts[r] +
//     rowlen[r] itself. Global row order in spack is NOT needed (gathers only
//     need per-row contiguity + a start pointer), so the global histogram +
//     3-kernel scan (subhist/scan_block/scan_bsum/scan_add) are DELETED.
//     4 fewer full-device drain/ramp boundaries (~8-10 us each, incl. the
//     single-block scan_bsum which was pure latency).
// -----------------------------------------------------------------------------
__global__ void bucket_kernel(const int* __restrict__ fr, const int* __restrict__ fc,
                              const float* __restrict__ fv,
                              const int* __restrict__ a1r, const int* __restrict__ a1c,
                              const float* __restrict__ a1v,
                              const int* __restrict__ a2r, const int* __restrict__ a2c,
                              const float* __restrict__ a2v,
                              int* __restrict__ bcur,
                              unsigned* __restrict__ gpack,
                              unsigned short* __restrict__ gmeta) {
    __shared__ int cnt8[8];
    __shared__ int offc[8];
    __shared__ int gbase[8];
    __shared__ unsigned spk[768];
    __shared__ unsigned short smeta[768];
    int t = threadIdx.x;
    if (t < 8) cnt8[t] = 0;
    __syncthreads();

    int e = blockIdx.x * 256 + t;        // NNZ = 3125 * 256, no tail
    int r[3]; unsigned pk[3]; int loc[3]; int pb[3];
    r[0] = __builtin_nontemporal_load(&fr[e]);
    pk[0] = pack_cv(__builtin_nontemporal_load(&fc[e]),
                    __builtin_nontemporal_load(&fv[e]));
    r[1] = __builtin_nontemporal_load(&a1r[e]);
    pk[1] = pack_cv(__builtin_nontemporal_load(&a1c[e]),
                    __builtin_nontemporal_load(&a1v[e]));
    r[2] = __builtin_nontemporal_load(&a2r[e]);
    pk[2] = pack_cv(__builtin_nontemporal_load(&a2c[e]),
                    __builtin_nontemporal_load(&a2v[e]));
#pragma unroll
    for (int s = 0; s < 3; ++s) {
        pb[s] = r[s] / PART_W;
        loc[s] = atomicAdd(&cnt8[pb[s]], 1);
    }
    __syncthreads();
    if (t < 8) gbase[t] = atomicAdd(&bcur[t], cnt8[t]);
    if (t == 0) {
        int acc = 0;
#pragma unroll
        for (int q = 0; q < 8; ++q) { offc[q] = acc; acc += cnt8[q]; }
    }
    __syncthreads();
#pragma unroll
    for (int s = 0; s < 3; ++s) {
        int pos = offc[pb[s]] + loc[s];
        spk[pos] = pk[s];
        smeta[pos] = (unsigned short)((s << 13) | (r[s] - pb[s] * PART_W));
    }
    __syncthreads();
#pragma unroll
    for (int k = 0; k < 3; ++k) {
        int i = t + k * 256;
        int q = 0;
#pragma unroll
        for (int b = 1; b < 8; ++b) q += (i >= offc[b]);
        int g = q * BCAP + gbase[q] + (i - offc[q]);
        gpack[g] = spk[i];
        gmeta[g] = smeta[i];
    }
}

// Pass B: partition bucket -> 64 sub-buckets (98-row ranges). blockIdx&7 = p.
__global__ void subbucket_kernel(const unsigned* __restrict__ gpack1,
                                 const unsigned short* __restrict__ gmeta1,
                                 const int* __restrict__ bcur,
                                 int* __restrict__ subcur,
                                 unsigned* __restrict__ gpack2,
                                 unsigned short* __restrict__ gmeta2) {
    int p = blockIdx.x & (NPART - 1);
    int chunk = blockIdx.x >> 3;
    int base = chunk * ENT_B;
    int n = bcur[p];
    int cnt = n - base;
    if (cnt <= 0) return;                // uniform across block
    if (cnt > ENT_B) cnt = ENT_B;
    __shared__ int c64[NSUB], off[NSUB], gb[NSUB];
    __shared__ unsigned spk[ENT_B];
    __shared__ unsigned short smt[ENT_B];
    int t = threadIdx.x;
    if (t < NSUB) c64[t] = 0;
    __syncthreads();
    unsigned pk[16]; unsigned short mt[16]; int loc[16]; int sb[16];
#pragma unroll
    for (int k = 0; k < 16; ++k) {
        int i = t + k * 256;
        if (i < cnt) {
            pk[k] = gpack1[p * BCAP + base + i];
            mt[k] = gmeta1[p * BCAP + base + i];
            sb[k] = (int)(mt[k] & 8191u) / SUBW;
            loc[k] = atomicAdd(&c64[sb[k]], 1);
        } else sb[k] = -1;
    }
    __syncthreads();
    if (t == 0) {
        int a = 0;
#pragma unroll
        for (int q = 0; q < NSUB; ++q) { off[q] = a; a += c64[q]; }
    }
    __syncthreads();
    if (t < NSUB && c64[t] > 0) gb[t] = atomicAdd(&subcur[p * NSUB + t], c64[t]);
    __syncthreads();
#pragma unroll
    for (int k = 0; k < 16; ++k) {
        if (sb[k] >= 0) {
            int pos = off[sb[k]] + loc[k];
            spk[pos] = pk[k];
            smt[pos] = mt[k];
        }
    }
    __syncthreads();
    for (int i = t; i < cnt; i += 256) {
        unsigned short m = smt[i];
        int s2 = (int)(m & 8191u) / SUBW;
        int g = (p * NSUB + s2) * SUBCAP + gb[s2] + (i - off[s2]);
        gpack2[g] = spk[i];
        gmeta2[g] = m;
    }
}

// Pass C: LDS counting sort of one sub-bucket; block reserves per-segment
// output ranges (atomic cursors, within-segment) and emits starts+rowlen.
// spack layout: seg s occupies [s*NNZ, (s+1)*NNZ) (each segment totals NNZ).
__global__ __launch_bounds__(512) void sort_write_kernel(
        const unsigned* __restrict__ gpack2,
        const unsigned short* __restrict__ gmeta2,
        const int* __restrict__ subcur,
        int* __restrict__ cur3,
        int* __restrict__ starts,
        int* __restrict__ rowlen,
        unsigned* __restrict__ spack) {
    int p = blockIdx.x & (NPART - 1);
    int sub = blockIdx.x >> 3;
    int n = subcur[p * NSUB + sub];
    __shared__ int h[512];
    __shared__ int e[512];
    __shared__ int cur[512];
    __shared__ int segbase[4];           // [0]=0, [1]=seg0 cnt.., [3]=n
    __shared__ int gbs[3];               // per-segment global (within-seg) base
    __shared__ unsigned sorted[SUBCAP];
    int t = threadIdx.x;
    h[t] = 0;
    __syncthreads();
    long base = (long)(p * NSUB + sub) * SUBCAP;
    unsigned pk[12]; short ky[12];
#pragma unroll
    for (int k = 0; k < 12; ++k) {           // SUBCAP = 12*512 exactly
        int i = t + k * 512;
        if (i < n) {
            pk[k] = gpack2[base + i];
            unsigned short m = gmeta2[base + i];
            int key = (int)(m >> 13) * SUBW + ((int)(m & 8191u) - sub * SUBW);
            ky[k] = (short)key;
            atomicAdd(&h[key], 1);
        } else ky[k] = -1;
    }
    __syncthreads();
    e[t] = h[t];
    __syncthreads();
    for (int off = 1; off < 512; off <<= 1) {
        int v = (t >= off) ? e[t - off] : 0;
        __syncthreads();
        e[t] += v;
        __syncthreads();
    }
    int excl = e[t] - h[t];
    __syncthreads();
    e[t] = excl;
    cur[t] = excl;
    if (t == 0) {
        segbase[0] = 0;
    }
    __syncthreads();
    if (t == 0) {
        segbase[1] = e[SUBW];
        segbase[2] = e[2 * SUBW];
        segbase[3] = n;
    }
    __syncthreads();
    if (t < 3) gbs[t] = atomicAdd(&cur3[t], segbase[t + 1] - segbase[t]);
    // scatter into LDS (concurrent with the t<3 reservations; disjoint memory)
#pragma unroll
    for (int k = 0; k < 12; ++k) {
        if (ky[k] >= 0) {
            int pos = atomicAdd(&cur[ky[k]], 1);
            sorted[pos] = pk[k];
        }
    }
    __syncthreads();
    // Emit row pointers + lengths for this block's 98 rows x 3 segments.
    if (t < 3 * SUBW) {
        int s = t / SUBW, d = t - s * SUBW;
        int rl = sub * SUBW + d;
        if (rl < PART_W) {
            int gr = s * N_NODES + p * PART_W + rl;
            starts[gr] = s * NNZ + gbs[s] + (e[t] - segbase[s]);
            rowlen[gr] = h[t];
        }
    }
    // Coalesced contiguous entry write-out (one chunk per segment).
    int s1 = segbase[1], s2 = segbase[2];
#pragma unroll
    for (int k = 0; k < 12; ++k) {
        int i = t + k * 512;
        if (i < n) {
            int sg = (i < s1) ? 0 : ((i < s2) ? 1 : 2);
            spack[sg * NNZ + gbs[sg] + (i - segbase[sg])] = sorted[i];
        }
    }
}

// -----------------------------------------------------------------------------
// Phase 1: per-row gather  xw{1,2}[r,:] = sum_e v_e * W{1,2}[c_e,:]
// Output in 32-dim-slice layout: xw[s][r][d32], s in [0,4), 64 B per row-slice.
// Row extent now from starts[r] + rowlen[r] (spack not globally row-ordered).
// -----------------------------------------------------------------------------
__global__ void feat_gather_kernel(const int* __restrict__ starts,
                                   const int* __restrict__ rowlen,
                                   const unsigned* __restrict__ spack,
                                   const float4* __restrict__ W1,
                                   const float4* __restrict__ W2,
                                   ushort4* __restrict__ xw1s,
                                   ushort4* __restrict__ xw2s) {
    int lane = threadIdx.x & 31;
    int sub  = threadIdx.x >> 5;
    int r = blockIdx.x * 8 + sub;
    if (r >= N_NODES) return;
    int s = starts[r];
    int e = s + rowlen[r];
    float4 a1 = make_float4(0.f, 0.f, 0.f, 0.f);
    float4 a2 = make_float4(0.f, 0.f, 0.f, 0.f);
    for (int base = s; base < e; base += 32) {
        int n = e - base;
        int m = (n < 32) ? n : 32;
        unsigned pk = (lane < m) ? spack[base + lane] : 0u;
        int j = 0;
        for (; j + 7 < m; j += 8) {
            unsigned pp[8]; float4 w1v[8]; float4 w2v[8];
#pragma unroll
            for (int k = 0; k < 8; ++k) pp[k] = __shfl(pk, j + k, 32);
#pragma unroll
            for (int k = 0; k < 8; ++k) {
                int c = upk_c(pp[k]);
                w1v[k] = W1[c * 32 + lane];
                w2v[k] = W2[c * 32 + lane];
            }
#pragma unroll
            for (int k = 0; k < 8; ++k) {
                float v = upk_v(pp[k]);
                a1.x += v * w1v[k].x; a1.y += v * w1v[k].y;
                a1.z += v * w1v[k].z; a1.w += v * w1v[k].w;
                a2.x += v * w2v[k].x; a2.y += v * w2v[k].y;
                a2.z += v * w2v[k].z; a2.w += v * w2v[k].w;
            }
        }
        for (; j + 3 < m; j += 4) {
            unsigned pp[4]; float4 w1v[4]; float4 w2v[4];
#pragma unroll
            for (int k = 0; k < 4; ++k) pp[k] = __shfl(pk, j + k, 32);
#pragma unroll
            for (int k = 0; k < 4; ++k) {
                int c = upk_c(pp[k]);
                w1v[k] = W1[c * 32 + lane];
                w2v[k] = W2[c * 32 + lane];
            }
#pragma unroll
            for (int k = 0; k < 4; ++k) {
                float v = upk_v(pp[k]);
                a1.x += v * w1v[k].x; a1.y += v * w1v[k].y;
                a1.z += v * w1v[k].z; a1.w += v * w1v[k].w;
                a2.x += v * w2v[k].x; a2.y += v * w2v[k].y;
                a2.z += v * w2v[k].z; a2.w += v * w2v[k].w;
            }
        }
        for (; j < m; ++j) {
            unsigned pj = __shfl(pk, j, 32);
            int c = upk_c(pj);
            float v = upk_v(pj);
            float4 w1 = W1[c * 32 + lane];
            float4 w2 = W2[c * 32 + lane];
            a1.x += v * w1.x; a1.y += v * w1.y; a1.z += v * w1.z; a1.w += v * w1.w;
            a2.x += v * w2.x; a2.y += v * w2.y; a2.z += v * w2.z; a2.w += v * w2.w;
        }
    }
    ushort4 q1, q2;
    q1.x = __half_as_ushort(__float2half(a1.x)); q1.y = __half_as_ushort(__float2half(a1.y));
    q1.z = __half_as_ushort(__float2half(a1.z)); q1.w = __half_as_ushort(__float2half(a1.w));
    q2.x = __half_as_ushort(__float2half(a2.x)); q2.y = __half_as_ushort(__float2half(a2.y));
    q2.z = __half_as_ushort(__float2half(a2.z)); q2.w = __half_as_ushort(__float2half(a2.w));
    // 32-dim-slice store: lanes {8k..8k+7} write one full 64 B line.
    size_t idx = (size_t)(lane >> 3) * (N_NODES * 8) + (size_t)r * 8 + (lane & 7);
    xw1s[idx] = q1;
    xw2s[idx] = q2;
}

// -----------------------------------------------------------------------------
// Phase 2 (round-9 structure): rel-split, 32-dim slices, full-line gathers.
// -----------------------------------------------------------------------------
__global__ __launch_bounds__(512) void adj_pass_rel0(
        const int* __restrict__ starts,
        const int* __restrict__ rowlen,
        const unsigned* __restrict__ spack,
        const ushort4* __restrict__ xws,
        vf4* __restrict__ out) {
    int s  = blockIdx.x & (ADJ_SL - 1);
    int rc = blockIdx.x >> 2;
    int g  = threadIdx.x >> 3;          // 64 row-groups per block
    int q  = threadIdx.x & 7;
    int r  = rc * 64 + g;
    bool valid = (r < N_NODES);
    vf4 acc = {0.f, 0.f, 0.f, 0.f};
    const ushort4* __restrict__ sl = xws + (size_t)s * (N_NODES * 8);
    size_t oidx = (size_t)r * 32 + s * 8 + q;

    int st = 0, en = 0;
    if (valid) {
        st = starts[N_NODES + r];
        en = st + rowlen[N_NODES + r];
    }
    for (int base = st; base < en; base += 16) {
        int m = en - base;
        unsigned pk0 = (q < m)     ? spack[base + q]     : 0u;
        unsigned pk1 = (8 + q < m) ? spack[base + 8 + q] : 0u;
        {
            unsigned pp[8]; ushort4 xx[8];
#pragma unroll
            for (int k = 0; k < 8; ++k) pp[k] = __shfl(pk0, k, 8);
#pragma unroll
            for (int k = 0; k < 8; ++k) xx[k] = sl[upk_c(pp[k]) * 8 + q];
#pragma unroll
            for (int k = 0; k < 8; ++k) {
                float v = upk_v(pp[k]);
                acc.x += v * h2f(xx[k].x); acc.y += v * h2f(xx[k].y);
                acc.z += v * h2f(xx[k].z); acc.w += v * h2f(xx[k].w);
            }
        }
        if (m <= 8) continue;
        {
            unsigned pp[8]; ushort4 xx[8];
#pragma unroll
            for (int k = 0; k < 8; ++k) pp[k] = __shfl(pk1, k, 8);
#pragma unroll
            for (int k = 0; k < 8; ++k) xx[k] = sl[upk_c(pp[k]) * 8 + q];
#pragma unroll
            for (int k = 0; k < 8; ++k) {
                float v = upk_v(pp[k]);
                acc.x += v * h2f(xx[k].x); acc.y += v * h2f(xx[k].y);
                acc.z += v * h2f(xx[k].z); acc.w += v * h2f(xx[k].w);
            }
        }
    }
    if (valid) __builtin_nontemporal_store(acc, &out[oidx]);   // raw partial sum
}

__global__ __launch_bounds__(512) void adj_pass_rel1(
        const int* __restrict__ starts,
        const int* __restrict__ rowlen,
        const unsigned* __restrict__ spack,
        const ushort4* __restrict__ xws,
        vf4* __restrict__ out) {
    int s  = blockIdx.x & (ADJ_SL - 1);
    int rc = blockIdx.x >> 2;
    int g  = threadIdx.x >> 3;
    int q  = threadIdx.x & 7;
    int r  = rc * 64 + g;
    bool valid = (r < N_NODES);
    vf4 acc = {0.f, 0.f, 0.f, 0.f};
    const ushort4* __restrict__ sl = xws + (size_t)s * (N_NODES * 8);
    size_t oidx = (size_t)r * 32 + s * 8 + q;

    int st = 0, en = 0;
    if (valid) {
        st = starts[2 * N_NODES + r];
        en = st + rowlen[2 * N_NODES + r];
    }
    vf4 prev = {0.f, 0.f, 0.f, 0.f};
    if (valid) prev = __builtin_nontemporal_load(&out[oidx]);  // early, overlaps loop

    for (int base = st; base < en; base += 16) {
        int m = en - base;
        unsigned pk0 = (q < m)     ? spack[base + q]     : 0u;
        unsigned pk1 = (8 + q < m) ? spack[base + 8 + q] : 0u;
        {
            unsigned pp[8]; ushort4 xx[8];
#pragma unroll
            for (int k = 0; k < 8; ++k) pp[k] = __shfl(pk0, k, 8);
#pragma unroll
            for (int k = 0; k < 8; ++k) xx[k] = sl[upk_c(pp[k]) * 8 + q];
#pragma unroll
            for (int k = 0; k < 8; ++k) {
                float v = upk_v(pp[k]);
                acc.x += v * h2f(xx[k].x); acc.y += v * h2f(xx[k].y);
                acc.z += v * h2f(xx[k].z); acc.w += v * h2f(xx[k].w);
            }
        }
        if (m <= 8) continue;
        {
            unsigned pp[8]; ushort4 xx[8];
#pragma unroll
            for (int k = 0; k < 8; ++k) pp[k] = __shfl(pk1, k, 8);
#pragma unroll
            for (int k = 0; k < 8; ++k) xx[k] = sl[upk_c(pp[k]) * 8 + q];
#pragma unroll
            for (int k = 0; k < 8; ++k) {
                float v = upk_v(pp[k]);
                acc.x += v * h2f(xx[k].x); acc.y += v * h2f(xx[k].y);
                acc.z += v * h2f(xx[k].z); acc.w += v * h2f(xx[k].w);
            }
        }
    }
    if (valid) {
        vf4 res;
        res.x = fmaxf(acc.x + prev.x, 0.f);
        res.y = fmaxf(acc.y + prev.y, 0.f);
        res.z = fmaxf(acc.z + prev.z, 0.f);
        res.w = fmaxf(acc.w + prev.w, 0.f);
        __builtin_nontemporal_store(res, &out[oidx]);
    }
}

extern "C" void kernel_launch(void* const* d_in, const int* in_sizes, int n_in,
                              void* d_out, int out_size, void* d_ws, size_t ws_size,
                              hipStream_t stream) {
    const int*   feat_row  = (const int*)  d_in[0];
    const int*   feat_col  = (const int*)  d_in[1];
    const float* feat_vals = (const float*)d_in[2];
    const int*   adj1_row  = (const int*)  d_in[3];
    const int*   adj1_col  = (const int*)  d_in[4];
    const float* adj1_vals = (const float*)d_in[5];
    const int*   adj2_row  = (const int*)  d_in[6];
    const int*   adj2_col  = (const int*)  d_in[7];
    const float* adj2_vals = (const float*)d_in[8];
    const float* W1        = (const float*)d_in[9];
    const float* W2        = (const float*)d_in[10];

    // Workspace layout. Bucket storage (~33.8 MB) is dead after sort_write,
    // so xw1s/xw2s (25.6 MB) alias it. Total footprint ~45 MB.
    char* ws = (char*)d_ws;
    unsigned* spack = (unsigned*)ws;            ws += (size_t)TOTAL_NNZ * 4;          // 9.6 MB
    int*      starts= (int*)ws;                 ws += (size_t)SCAN_N * 4;             // 600 KB
    int*      rowlen= (int*)ws;                 ws += (size_t)SCAN_N * 4;             // 600 KB
    int*      bcur  = (int*)ws;                 ws += 16 * 4;                         // 8 used
    int*      subcur= (int*)ws;                 ws += (size_t)NPART * NSUB * 4;       // 2 KB
    int*      cur3  = (int*)ws;                 ws += 16 * 4;                         // 3 used
    char*     bkt   = ws;                                                             // bucket region
    unsigned* gpack1 = (unsigned*)bkt;
    unsigned short* gmeta1 = (unsigned short*)(bkt + (size_t)NPART * BCAP * 4);
    unsigned* gpack2 = (unsigned*)(bkt + (size_t)NPART * BCAP * 6);
    unsigned short* gmeta2 = (unsigned short*)(bkt + (size_t)NPART * BCAP * 6
                                                  + (size_t)NPART * NSUB * SUBCAP * 4);
    ushort4*  xw1s  = (ushort4*)bkt;                                     // alias (after C)
    ushort4*  xw2s  = (ushort4*)(bkt + (size_t)N_NODES * OUT_DIM * 2);   // alias

    // Zero cursors: bcur(16) + subcur(512) + cur3(16), contiguous.
    (void)hipMemsetAsync(bcur, 0, (16 + NPART * NSUB + 16) * sizeof(int), stream);

    const int block = 256;

    // A: single read of all 9 streams, LDS-bucket by row partition.
    bucket_kernel<<<NNZ / block, block, 0, stream>>>(
        feat_row, feat_col, feat_vals,
        adj1_row, adj1_col, adj1_vals,
        adj2_row, adj2_col, adj2_vals,
        bcur, gpack1, gmeta1);

    // B: partition bucket -> 64 sub-buckets (XCD-local reads, blockIdx&7 = p).
    subbucket_kernel<<<NPART * BBLK_B, block, 0, stream>>>(
        gpack1, gmeta1, bcur, subcur, gpack2, gmeta2);

    // C: LDS counting sort per sub-bucket; self-allocated output ranges,
    // emits starts+rowlen directly (no global histogram/scan kernels).
    sort_write_kernel<<<NPART * NSUB, 512, 0, stream>>>(
        gpack2, gmeta2, subcur, cur3, starts, rowlen, spack);

    const int grid_rows = N_NODES / 8;                           // 6250 blocks, 8 rows each
    feat_gather_kernel<<<grid_rows, 256, 0, stream>>>(
        starts, rowlen, spack, (const float4*)W1, (const float4*)W2, xw1s, xw2s);

    // Phase 2: rel-split, 32-dim slices, full-line gathers.
    adj_pass_rel0<<<ADJ_SL * ADJ_RC, 512, 0, stream>>>(
        starts, rowlen, spack, xw1s, (vf4*)d_out);
    adj_pass_rel1<<<ADJ_SL * ADJ_RC, 512, 0, stream>>>(
        starts, rowlen, spack, xw2s, (vf4*)d_out);
}

// Round 14
// 252.153 us; speedup vs baseline: 1.2475x; 1.0290x over previous
//
#include <hip/hip_runtime.h>
#include <hip/hip_fp16.h>

// Problem constants (fixed by the reference setup)
#define N_NODES 50000
#define IN_DIM 256
#define OUT_DIM 128
#define NNZ 800000          // nnz for feat, adj1, adj2 each
#define SCAN_N (3 * N_NODES)        // 150000 row pointers (feat | adj1 | adj2)
#define TOTAL_NNZ (3 * NNZ)         // 2.4M sorted entries
#define NPART 8                      // one row-partition per XCD
#define PART_W (N_NODES / NPART)     // 6250 rows per partition

// Level-1 per-partition bucket capacity.
#define BCAP 310016

// Level-2 sub-buckets: 64 per partition, 98 rows each.
#define NSUB 64
#define SUBW 98
#define SUBCAP 6144
#define ENT_B 4096
#define BBLK_B ((BCAP + ENT_B - 1) / ENT_B)   // 76 blocks per partition

// adj phase: TWO dispatches (rel0 raw-acc, rel1 acc+relu); 32-dim slices
// (64 B/row-slice) -> per-XCD working set 3.2 MB, L2-resident (round-9: works).
#define ADJ_SL 4
#define ADJ_RC ((N_NODES + 63) / 64)  // 782 row-chunks of 64 rows

// Native clang vector types.
typedef float vf4 __attribute__((ext_vector_type(4)));

// Packed entry: [col:16 | fp16(val):16].  adj cols < 50000 < 65536, feat cols < 256.
static __device__ __forceinline__ unsigned pack_cv(int c, float v) {
    return ((unsigned)c << 16) | (unsigned)__half_as_ushort(__float2half(v));
}
static __device__ __forceinline__ int   upk_c(unsigned pk) { return (int)(pk >> 16); }
static __device__ __forceinline__ float upk_v(unsigned pk) {
    return __half2float(__ushort_as_half((unsigned short)(pk & 0xffffu)));
}
static __device__ __forceinline__ float h2f(unsigned short h) {
    return __half2float(__ushort_as_half(h));
}
static __device__ __forceinline__ unsigned pk2h(float x, float y) {
    return (unsigned)__half_as_ushort(__float2half(x))
         | ((unsigned)__half_as_ushort(__float2half(y)) << 16);
}

// -----------------------------------------------------------------------------
// wprep: interleave W1|W2 into ONE fp16 table.
//   Wc[c*32 + l] (uint4, 16 B) = { w1[c, 4l..4l+3], w2[c, 4l..4l+3] } as 8 halves.
// feat_gather then needs ONE 16 B load per edge for BOTH tables (8 L2
// line-requests/edge instead of 16 with two fp32 row reads). Random-line
// request rate is the measured wall for gather kernels (round 7 calibration:
// 12.8M requests ~ 74 us); halving requests is the proven lever (rounds 8/9).
// -----------------------------------------------------------------------------
__global__ void wprep_kernel(const float* __restrict__ W1,
                             const float* __restrict__ W2,
                             uint4* __restrict__ Wc) {
    int idx = blockIdx.x * 256 + threadIdx.x;   // 8192 = 256 rows * 32 lanes
    const float4* w1 = (const float4*)W1;
    const float4* w2 = (const float4*)W2;
    float4 a = w1[idx];
    float4 b = w2[idx];
    uint4 o;
    o.x = pk2h(a.x, a.y);
    o.y = pk2h(a.z, a.w);
    o.z = pk2h(b.x, b.y);
    o.w = pk2h(b.z, b.w);
    Wc[idx] = o;
}

// -----------------------------------------------------------------------------
// CSR build, THREE kernels (round-11 pipeline verbatim — passed at 259.5 us):
//   A (bucket_kernel):    read every edge once, LDS-group by partition (row/6250).
//   B (subbucket_kernel): partition bucket -> 64 sub-buckets (98-row ranges).
//   C (sort_write_kernel): per-sub-bucket LDS counting sort; block reserves
//     per-segment output ranges via 3 atomic cursors, emits starts+rowlen.
// -----------------------------------------------------------------------------
__global__ void bucket_kernel(const int* __restrict__ fr, const int* __restrict__ fc,
                              const float* __restrict__ fv,
                              const int* __restrict__ a1r, const int* __restrict__ a1c,
                              const float* __restrict__ a1v,
                              const int* __restrict__ a2r, const int* __restrict__ a2c,
                              const float* __restrict__ a2v,
                              int* __restrict__ bcur,
                              unsigned* __restrict__ gpack,
                              unsigned short* __restrict__ gmeta) {
    __shared__ int cnt8[8];
    __shared__ int offc[8];
    __shared__ int gbase[8];
    __shared__ unsigned spk[768];
    __shared__ unsigned short smeta[768];
    int t = threadIdx.x;
    if (t < 8) cnt8[t] = 0;
    __syncthreads();

    int e = blockIdx.x * 256 + t;        // NNZ = 3125 * 256, no tail
    int r[3]; unsigned pk[3]; int loc[3]; int pb[3];
    r[0] = __builtin_nontemporal_load(&fr[e]);
    pk[0] = pack_cv(__builtin_nontemporal_load(&fc[e]),
                    __builtin_nontemporal_load(&fv[e]));
    r[1] = __builtin_nontemporal_load(&a1r[e]);
    pk[1] = pack_cv(__builtin_nontemporal_load(&a1c[e]),
                    __builtin_nontemporal_load(&a1v[e]));
    r[2] = __builtin_nontemporal_load(&a2r[e]);
    pk[2] = pack_cv(__builtin_nontemporal_load(&a2c[e]),
                    __builtin_nontemporal_load(&a2v[e]));
#pragma unroll
    for (int s = 0; s < 3; ++s) {
        pb[s] = r[s] / PART_W;
        loc[s] = atomicAdd(&cnt8[pb[s]], 1);
    }
    __syncthreads();
    if (t < 8) gbase[t] = atomicAdd(&bcur[t], cnt8[t]);
    if (t == 0) {
        int acc = 0;
#pragma unroll
        for (int q = 0; q < 8; ++q) { offc[q] = acc; acc += cnt8[q]; }
    }
    __syncthreads();
#pragma unroll
    for (int s = 0; s < 3; ++s) {
        int pos = offc[pb[s]] + loc[s];
        spk[pos] = pk[s];
        smeta[pos] = (unsigned short)((s << 13) | (r[s] - pb[s] * PART_W));
    }
    __syncthreads();
#pragma unroll
    for (int k = 0; k < 3; ++k) {
        int i = t + k * 256;
        int q = 0;
#pragma unroll
        for (int b = 1; b < 8; ++b) q += (i >= offc[b]);
        int g = q * BCAP + gbase[q] + (i - offc[q]);
        gpack[g] = spk[i];
        gmeta[g] = smeta[i];
    }
}

// Pass B: partition bucket -> 64 sub-buckets (98-row ranges). blockIdx&7 = p.
__global__ void subbucket_kernel(const unsigned* __restrict__ gpack1,
                                 const unsigned short* __restrict__ gmeta1,
                                 const int* __restrict__ bcur,
                                 int* __restrict__ subcur,
                                 unsigned* __restrict__ gpack2,
                                 unsigned short* __restrict__ gmeta2) {
    int p = blockIdx.x & (NPART - 1);
    int chunk = blockIdx.x >> 3;
    int base = chunk * ENT_B;
    int n = bcur[p];
    int cnt = n - base;
    if (cnt <= 0) return;                // uniform across block
    if (cnt > ENT_B) cnt = ENT_B;
    __shared__ int c64[NSUB];
    __shared__ int off[NSUB];
    __shared__ int gb[NSUB];
    __shared__ unsigned spk[ENT_B];
    __shared__ unsigned short smt[ENT_B];
    int t = threadIdx.x;
    if (t < NSUB) c64[t] = 0;
    __syncthreads();
    unsigned pk[16]; unsigned short mt[16]; int loc[16]; int sb[16];
#pragma unroll
    for (int k = 0; k < 16; ++k) {
        int i = t + k * 256;
        if (i < cnt) {
            pk[k] = gpack1[p * BCAP + base + i];
            mt[k] = gmeta1[p * BCAP + base + i];
            sb[k] = (int)(mt[k] & 8191u) / SUBW;
            loc[k] = atomicAdd(&c64[sb[k]], 1);
        } else sb[k] = -1;
    }
    __syncthreads();
    if (t == 0) {
        int a = 0;
#pragma unroll
        for (int q = 0; q < NSUB; ++q) { off[q] = a; a += c64[q]; }
    }
    __syncthreads();
    if (t < NSUB && c64[t] > 0) gb[t] = atomicAdd(&subcur[p * NSUB + t], c64[t]);
    __syncthreads();
#pragma unroll
    for (int k = 0; k < 16; ++k) {
        if (sb[k] >= 0) {
            int pos = off[sb[k]] + loc[k];
            spk[pos] = pk[k];
            smt[pos] = mt[k];
        }
    }
    __syncthreads();
    for (int i = t; i < cnt; i += 256) {
        unsigned short m = smt[i];
        int s2 = (int)(m & 8191u) / SUBW;
        int g = (p * NSUB + s2) * SUBCAP + gb[s2] + (i - off[s2]);
        gpack2[g] = spk[i];
        gmeta2[g] = m;
    }
}

// Pass C: LDS counting sort of one sub-bucket; block reserves per-segment
// output ranges (atomic cursors) and emits starts+rowlen.
// spack layout: seg s occupies [s*NNZ, (s+1)*NNZ).
__global__ __launch_bounds__(512) void sort_write_kernel(
        const unsigned* __restrict__ gpack2,
        const unsigned short* __restrict__ gmeta2,
        const int* __restrict__ subcur,
        int* __restrict__ cur3,
        int* __restrict__ starts,
        int* __restrict__ rowlen,
        unsigned* __restrict__ spack) {
    int p = blockIdx.x & (NPART - 1);
    int sub = blockIdx.x >> 3;
    int n = subcur[p * NSUB + sub];
    __shared__ int h[512];
    __shared__ int e[512];
    __shared__ int cur[512];
    __shared__ int segbase[4];           // [0]=0 .. [3]=n
    __shared__ int gbs[3];               // per-segment global (within-seg) base
    __shared__ unsigned sorted[SUBCAP];
    int t = threadIdx.x;
    h[t] = 0;
    __syncthreads();
    long base = (long)(p * NSUB + sub) * SUBCAP;
    unsigned pk[12]; short ky[12];
#pragma unroll
    for (int k = 0; k < 12; ++k) {           // SUBCAP = 12*512 exactly
        int i = t + k * 512;
        if (i < n) {
            pk[k] = gpack2[base + i];
            unsigned short m = gmeta2[base + i];
            int key = (int)(m >> 13) * SUBW + ((int)(m & 8191u) - sub * SUBW);
            ky[k] = (short)key;
            atomicAdd(&h[key], 1);
        } else ky[k] = -1;
    }
    __syncthreads();
    e[t] = h[t];
    __syncthreads();
    for (int off = 1; off < 512; off <<= 1) {
        int v = (t >= off) ? e[t - off] : 0;
        __syncthreads();
        e[t] += v;
        __syncthreads();
    }
    int excl = e[t] - h[t];
    __syncthreads();
    e[t] = excl;
    cur[t] = excl;
    __syncthreads();
    if (t == 0) {
        segbase[0] = 0;
        segbase[1] = e[SUBW];
        segbase[2] = e[2 * SUBW];
        segbase[3] = n;
    }
    __syncthreads();
    if (t < 3) gbs[t] = atomicAdd(&cur3[t], segbase[t + 1] - segbase[t]);
    // LDS scatter (concurrent with the t<3 reservations; disjoint memory)
#pragma unroll
    for (int k = 0; k < 12; ++k) {
        if (ky[k] >= 0) {
            int pos = atomicAdd(&cur[ky[k]], 1);
            sorted[pos] = pk[k];
        }
    }
    __syncthreads();
    // Emit row pointers + lengths for this block's 98 rows x 3 segments.
    if (t < 3 * SUBW) {
        int s = t / SUBW, d = t - s * SUBW;
        int rl = sub * SUBW + d;
        if (rl < PART_W) {
            int gr = s * N_NODES + p * PART_W + rl;
            starts[gr] = s * NNZ + gbs[s] + (e[t] - segbase[s]);
            rowlen[gr] = h[t];
        }
    }
    // Coalesced contiguous entry write-out (one chunk per segment).
    int s1 = segbase[1], s2 = segbase[2];
#pragma unroll
    for (int k = 0; k < 12; ++k) {
        int i = t + k * 512;
        if (i < n) {
            int sg = (i < s1) ? 0 : ((i < s2) ? 1 : 2);
            spack[sg * NNZ + gbs[sg] + (i - segbase[sg])] = sorted[i];
        }
    }
}

// -----------------------------------------------------------------------------
// Phase 1: per-row gather  xw{1,2}[r,:] = sum_e v_e * W{1,2}[c_e,:]
// fp16 interleaved table: ONE uint4 (16 B) load per edge covers BOTH tables.
// Output in 32-dim-slice layout: xw[s][r][d32], s in [0,4), 64 B per row-slice.
// -----------------------------------------------------------------------------
__global__ void feat_gather_kernel(const int* __restrict__ starts,
                                   const int* __restrict__ rowlen,
                                   const unsigned* __restrict__ spack,
                                   const uint4* __restrict__ Wc,
                                   ushort4* __restrict__ xw1s,
                                   ushort4* __restrict__ xw2s) {
    int lane = threadIdx.x & 31;
    int sub  = threadIdx.x >> 5;
    int r = blockIdx.x * 8 + sub;
    if (r >= N_NODES) return;
    int s = starts[r];
    int e = s + rowlen[r];
    float4 a1 = make_float4(0.f, 0.f, 0.f, 0.f);
    float4 a2 = make_float4(0.f, 0.f, 0.f, 0.f);
    for (int base = s; base < e; base += 32) {
        int n = e - base;
        int m = (n < 32) ? n : 32;
        unsigned pk = (lane < m) ? spack[base + lane] : 0u;
        int j = 0;
        for (; j + 7 < m; j += 8) {
            unsigned pp[8]; uint4 wv[8];
#pragma unroll
            for (int k = 0; k < 8; ++k) pp[k] = __shfl(pk, j + k, 32);
#pragma unroll
            for (int k = 0; k < 8; ++k) wv[k] = Wc[upk_c(pp[k]) * 32 + lane];
#pragma unroll
            for (int k = 0; k < 8; ++k) {
                float v = upk_v(pp[k]);
                a1.x += v * h2f((unsigned short)(wv[k].x & 0xffffu));
                a1.y += v * h2f((unsigned short)(wv[k].x >> 16));
                a1.z += v * h2f((unsigned short)(wv[k].y & 0xffffu));
                a1.w += v * h2f((unsigned short)(wv[k].y >> 16));
                a2.x += v * h2f((unsigned short)(wv[k].z & 0xffffu));
                a2.y += v * h2f((unsigned short)(wv[k].z >> 16));
                a2.z += v * h2f((unsigned short)(wv[k].w & 0xffffu));
                a2.w += v * h2f((unsigned short)(wv[k].w >> 16));
            }
        }
        for (; j < m; ++j) {
            unsigned pj = __shfl(pk, j, 32);
            float v = upk_v(pj);
            uint4 wv = Wc[upk_c(pj) * 32 + lane];
            a1.x += v * h2f((unsigned short)(wv.x & 0xffffu));
            a1.y += v * h2f((unsigned short)(wv.x >> 16));
            a1.z += v * h2f((unsigned short)(wv.y & 0xffffu));
            a1.w += v * h2f((unsigned short)(wv.y >> 16));
            a2.x += v * h2f((unsigned short)(wv.z & 0xffffu));
            a2.y += v * h2f((unsigned short)(wv.z >> 16));
            a2.z += v * h2f((unsigned short)(wv.w & 0xffffu));
            a2.w += v * h2f((unsigned short)(wv.w >> 16));
        }
    }
    ushort4 q1, q2;
    q1.x = __half_as_ushort(__float2half(a1.x)); q1.y = __half_as_ushort(__float2half(a1.y));
    q1.z = __half_as_ushort(__float2half(a1.z)); q1.w = __half_as_ushort(__float2half(a1.w));
    q2.x = __half_as_ushort(__float2half(a2.x)); q2.y = __half_as_ushort(__float2half(a2.y));
    q2.z = __half_as_ushort(__float2half(a2.z)); q2.w = __half_as_ushort(__float2half(a2.w));
    // 32-dim-slice store: lanes {8k..8k+7} write one full 64 B line.
    size_t idx = (size_t)(lane >> 3) * (N_NODES * 8) + (size_t)r * 8 + (lane & 7);
    xw1s[idx] = q1;
    xw2s[idx] = q2;
}

// -----------------------------------------------------------------------------
// Phase 2 (round-9 structure): rel-split, 32-dim slices, full-line gathers.
// -----------------------------------------------------------------------------
__global__ __launch_bounds__(512) void adj_pass_rel0(
        const int* __restrict__ starts,
        const int* __restrict__ rowlen,
        const unsigned* __restrict__ spack,
        const ushort4* __restrict__ xws,
        vf4* __restrict__ out) {
    int s  = blockIdx.x & (ADJ_SL - 1);
    int rc = blockIdx.x >> 2;
    int g  = threadIdx.x >> 3;          // 64 row-groups per block
    int q  = threadIdx.x & 7;
    int r  = rc * 64 + g;
    bool valid = (r < N_NODES);
    vf4 acc = {0.f, 0.f, 0.f, 0.f};
    const ushort4* __restrict__ sl = xws + (size_t)s * (N_NODES * 8);
    size_t oidx = (size_t)r * 32 + s * 8 + q;

    int st = 0, en = 0;
    if (valid) {
        st = starts[N_NODES + r];
        en = st + rowlen[N_NODES + r];
    }
    for (int base = st; base < en; base += 16) {
        int m = en - base;
        unsigned pk0 = (q < m)     ? spack[base + q]     : 0u;
        unsigned pk1 = (8 + q < m) ? spack[base + 8 + q] : 0u;
        {
            unsigned pp[8]; ushort4 xx[8];
#pragma unroll
            for (int k = 0; k < 8; ++k) pp[k] = __shfl(pk0, k, 8);
#pragma unroll
            for (int k = 0; k < 8; ++k) xx[k] = sl[upk_c(pp[k]) * 8 + q];
#pragma unroll
            for (int k = 0; k < 8; ++k) {
                float v = upk_v(pp[k]);
                acc.x += v * h2f(xx[k].x); acc.y += v * h2f(xx[k].y);
                acc.z += v * h2f(xx[k].z); acc.w += v * h2f(xx[k].w);
            }
        }
        if (m <= 8) continue;
        {
            unsigned pp[8]; ushort4 xx[8];
#pragma unroll
            for (int k = 0; k < 8; ++k) pp[k] = __shfl(pk1, k, 8);
#pragma unroll
            for (int k = 0; k < 8; ++k) xx[k] = sl[upk_c(pp[k]) * 8 + q];
#pragma unroll
            for (int k = 0; k < 8; ++k) {
                float v = upk_v(pp[k]);
                acc.x += v * h2f(xx[k].x); acc.y += v * h2f(xx[k].y);
                acc.z += v * h2f(xx[k].z); acc.w += v * h2f(xx[k].w);
            }
        }
    }
    if (valid) __builtin_nontemporal_store(acc, &out[oidx]);   // raw partial sum
}

__global__ __launch_bounds__(512) void adj_pass_rel1(
        const int* __restrict__ starts,
        const int* __restrict__ rowlen,
        const unsigned* __restrict__ spack,
        const ushort4* __restrict__ xws,
        vf4* __restrict__ out) {
    int s  = blockIdx.x & (ADJ_SL - 1);
    int rc = blockIdx.x >> 2;
    int g  = threadIdx.x >> 3;
    int q  = threadIdx.x & 7;
    int r  = rc * 64 + g;
    bool valid = (r < N_NODES);
    vf4 acc = {0.f, 0.f, 0.f, 0.f};
    const ushort4* __restrict__ sl = xws + (size_t)s * (N_NODES * 8);
    size_t oidx = (size_t)r * 32 + s * 8 + q;

    int st = 0, en = 0;
    if (valid) {
        st = starts[2 * N_NODES + r];
        en = st + rowlen[2 * N_NODES + r];
    }
    vf4 prev = {0.f, 0.f, 0.f, 0.f};
    if (valid) prev = __builtin_nontemporal_load(&out[oidx]);  // early, overlaps loop

    for (int base = st; base < en; base += 16) {
        int m = en - base;
        unsigned pk0 = (q < m)     ? spack[base + q]     : 0u;
        unsigned pk1 = (8 + q < m) ? spack[base + 8 + q] : 0u;
        {
            unsigned pp[8]; ushort4 xx[8];
#pragma unroll
            for (int k = 0; k < 8; ++k) pp[k] = __shfl(pk0, k, 8);
#pragma unroll
            for (int k = 0; k < 8; ++k) xx[k] = sl[upk_c(pp[k]) * 8 + q];
#pragma unroll
            for (int k = 0; k < 8; ++k) {
                float v = upk_v(pp[k]);
                acc.x += v * h2f(xx[k].x); acc.y += v * h2f(xx[k].y);
                acc.z += v * h2f(xx[k].z); acc.w += v * h2f(xx[k].w);
            }
        }
        if (m <= 8) continue;
        {
            unsigned pp[8]; ushort4 xx[8];
#pragma unroll
            for (int k = 0; k < 8; ++k) pp[k] = __shfl(pk1, k, 8);
#pragma unroll
            for (int k = 0; k < 8; ++k) xx[k] = sl[upk_c(pp[k]) * 8 + q];
#pragma unroll
            for (int k = 0; k < 8; ++k) {
                float v = upk_v(pp[k]);
                acc.x += v * h2f(xx[k].x); acc.y += v * h2f(xx[k].y);
                acc.z += v * h2f(xx[k].z); acc.w += v * h2f(xx[k].w);
            }
        }
    }
    if (valid) {
        vf4 res;
        res.x = fmaxf(acc.x + prev.x, 0.f);
        res.y = fmaxf(acc.y + prev.y, 0.f);
        res.z = fmaxf(acc.z + prev.z, 0.f);
        res.w = fmaxf(acc.w + prev.w, 0.f);
        __builtin_nontemporal_store(res, &out[oidx]);
    }
}

extern "C" void kernel_launch(void* const* d_in, const int* in_sizes, int n_in,
                              void* d_out, int out_size, void* d_ws, size_t ws_size,
                              hipStream_t stream) {
    const int*   feat_row  = (const int*)  d_in[0];
    const int*   feat_col  = (const int*)  d_in[1];
    const float* feat_vals = (const float*)d_in[2];
    const int*   adj1_row  = (const int*)  d_in[3];
    const int*   adj1_col  = (const int*)  d_in[4];
    const float* adj1_vals = (const float*)d_in[5];
    const int*   adj2_row  = (const int*)  d_in[6];
    const int*   adj2_col  = (const int*)  d_in[7];
    const float* adj2_vals = (const float*)d_in[8];
    const float* W1        = (const float*)d_in[9];
    const float* W2        = (const float*)d_in[10];

    // Workspace layout. Bucket storage (~33.8 MB) is dead after sort_write,
    // so xw1s/xw2s (25.6 MB) alias it. Total footprint ~45 MB.
    char* ws = (char*)d_ws;
    unsigned* spack = (unsigned*)ws;            ws += (size_t)TOTAL_NNZ * 4;          // 9.6 MB
    int*      starts= (int*)ws;                 ws += (size_t)SCAN_N * 4;             // 600 KB
    int*      rowlen= (int*)ws;                 ws += (size_t)SCAN_N * 4;             // 600 KB
    int*      bcur  = (int*)ws;                 ws += 16 * 4;                         // 8 used
    int*      subcur= (int*)ws;                 ws += (size_t)NPART * NSUB * 4;       // 2 KB
    int*      cur3  = (int*)ws;                 ws += 16 * 4;                         // 3 used
    uint4*    Wc    = (uint4*)ws;               ws += (size_t)256 * 32 * 16;          // 128 KB
    char*     bkt   = ws;                                                             // bucket region
    unsigned* gpack1 = (unsigned*)bkt;
    unsigned short* gmeta1 = (unsigned short*)(bkt + (size_t)NPART * BCAP * 4);
    unsigned* gpack2 = (unsigned*)(bkt + (size_t)NPART * BCAP * 6);
    unsigned short* gmeta2 = (unsigned short*)(bkt + (size_t)NPART * BCAP * 6
                                                  + (size_t)NPART * NSUB * SUBCAP * 4);
    ushort4*  xw1s  = (ushort4*)bkt;                                     // alias (after C)
    ushort4*  xw2s  = (ushort4*)(bkt + (size_t)N_NODES * OUT_DIM * 2);   // alias

    // Zero cursors: bcur(16) + subcur(512) + cur3(16), contiguous.
    (void)hipMemsetAsync(bcur, 0, (16 + NPART * NSUB + 16) * sizeof(int), stream);

    const int block = 256;

    // W prep: interleaved fp16 table (independent of the sort).
    wprep_kernel<<<32, block, 0, stream>>>(W1, W2, Wc);

    // A: single read of all 9 streams, LDS-bucket by row partition.
    bucket_kernel<<<NNZ / block, block, 0, stream>>>(
        feat_row, feat_col, feat_vals,
        adj1_row, adj1_col, adj1_vals,
        adj2_row, adj2_col, adj2_vals,
        bcur, gpack1, gmeta1);

    // B: partition bucket -> 64 sub-buckets (XCD-local reads, blockIdx&7 = p).
    subbucket_kernel<<<NPART * BBLK_B, block, 0, stream>>>(
        gpack1, gmeta1, bcur, subcur, gpack2, gmeta2);

    // C: LDS counting sort per sub-bucket; self-allocated output ranges,
    // emits starts+rowlen directly (no global histogram/scan kernels).
    sort_write_kernel<<<NPART * NSUB, 512, 0, stream>>>(
        gpack2, gmeta2, subcur, cur3, starts, rowlen, spack);

    const int grid_rows = N_NODES / 8;                           // 6250 blocks, 8 rows each
    feat_gather_kernel<<<grid_rows, 256, 0, stream>>>(
        starts, rowlen, spack, Wc, xw1s, xw2s);

    // Phase 2: rel-split, 32-dim slices, full-line gathers.
    adj_pass_rel0<<<ADJ_SL * ADJ_RC, 512, 0, stream>>>(
        starts, rowlen, spack, xw1s, (vf4*)d_out);
    adj_pass_rel1<<<ADJ_SL * ADJ_RC, 512, 0, stream>>>(
        starts, rowlen, spack, xw2s, (vf4*)d_out);
}

// Round 15
// 251.005 us; speedup vs baseline: 1.2532x; 1.0046x over previous
//
#include <hip/hip_runtime.h>
#include <hip/hip_fp16.h>

// Problem constants (fixed by the reference setup)
#define N_NODES 50000
#define IN_DIM 256
#define OUT_DIM 128
#define NNZ 800000          // nnz for feat, adj1, adj2 each
#define SCAN_N (3 * N_NODES)        // 150000 row pointers (feat | adj1 | adj2)
#define TOTAL_NNZ (3 * NNZ)         // 2.4M sorted entries
#define NPART 8                      // one row-partition per XCD
#define PART_W (N_NODES / NPART)     // 6250 rows per partition

// Level-1 per-partition bucket capacity.
#define BCAP 310016

// Level-2 sub-buckets: 64 per partition, 98 rows each.
#define NSUB 64
#define SUBW 98
#define SUBCAP 6144
#define ENT_B 4096
#define BBLK_B ((BCAP + ENT_B - 1) / ENT_B)   // 76 blocks per partition

// adj phase: ONE fused dispatch (rel0 then rel1 per row); 32-dim slices.
// Per-phase working set per XCD = one table slice = 3.2 MB (L2-resident);
// the rel0->rel1 transition briefly mixes both slices — FETCH_SIZE will show
// whether residency survives (that measurement is this round's purpose).
#define ADJ_SL 4
#define ADJ_RC ((N_NODES + 63) / 64)  // 782 row-chunks of 64 rows

// Native clang vector types.
typedef float vf4 __attribute__((ext_vector_type(4)));

// Packed entry: [col:16 | fp16(val):16].  adj cols < 50000 < 65536, feat cols < 256.
static __device__ __forceinline__ unsigned pack_cv(int c, float v) {
    return ((unsigned)c << 16) | (unsigned)__half_as_ushort(__float2half(v));
}
static __device__ __forceinline__ int   upk_c(unsigned pk) { return (int)(pk >> 16); }
static __device__ __forceinline__ float upk_v(unsigned pk) {
    return __half2float(__ushort_as_half((unsigned short)(pk & 0xffffu)));
}
static __device__ __forceinline__ float h2f(unsigned short h) {
    return __half2float(__ushort_as_half(h));
}
static __device__ __forceinline__ unsigned pk2h(float x, float y) {
    return (unsigned)__half_as_ushort(__float2half(x))
         | ((unsigned)__half_as_ushort(__float2half(y)) << 16);
}

// -----------------------------------------------------------------------------
// wprep: interleave W1|W2 into ONE fp16 table (cache-resident, 128 KB).
// -----------------------------------------------------------------------------
__global__ void wprep_kernel(const float* __restrict__ W1,
                             const float* __restrict__ W2,
                             uint4* __restrict__ Wc) {
    int idx = blockIdx.x * 256 + threadIdx.x;   // 8192 = 256 rows * 32 lanes
    const float4* w1 = (const float4*)W1;
    const float4* w2 = (const float4*)W2;
    float4 a = w1[idx];
    float4 b = w2[idx];
    uint4 o;
    o.x = pk2h(a.x, a.y);
    o.y = pk2h(a.z, a.w);
    o.z = pk2h(b.x, b.y);
    o.w = pk2h(b.z, b.w);
    Wc[idx] = o;
}

// -----------------------------------------------------------------------------
// CSR build, THREE kernels (round-11/14 pipeline verbatim — KNOWN-GOOD).
// -----------------------------------------------------------------------------
__global__ void bucket_kernel(const int* __restrict__ fr, const int* __restrict__ fc,
                              const float* __restrict__ fv,
                              const int* __restrict__ a1r, const int* __restrict__ a1c,
                              const float* __restrict__ a1v,
                              const int* __restrict__ a2r, const int* __restrict__ a2c,
                              const float* __restrict__ a2v,
                              int* __restrict__ bcur,
                              unsigned* __restrict__ gpack,
                              unsigned short* __restrict__ gmeta) {
    __shared__ int cnt8[8];
    __shared__ int offc[8];
    __shared__ int gbase[8];
    __shared__ unsigned spk[768];
    __shared__ unsigned short smeta[768];
    int t = threadIdx.x;
    if (t < 8) cnt8[t] = 0;
    __syncthreads();

    int e = blockIdx.x * 256 + t;        // NNZ = 3125 * 256, no tail
    int r[3]; unsigned pk[3]; int loc[3]; int pb[3];
    r[0] = __builtin_nontemporal_load(&fr[e]);
    pk[0] = pack_cv(__builtin_nontemporal_load(&fc[e]),
                    __builtin_nontemporal_load(&fv[e]));
    r[1] = __builtin_nontemporal_load(&a1r[e]);
    pk[1] = pack_cv(__builtin_nontemporal_load(&a1c[e]),
                    __builtin_nontemporal_load(&a1v[e]));
    r[2] = __builtin_nontemporal_load(&a2r[e]);
    pk[2] = pack_cv(__builtin_nontemporal_load(&a2c[e]),
                    __builtin_nontemporal_load(&a2v[e]));
#pragma unroll
    for (int s = 0; s < 3; ++s) {
        pb[s] = r[s] / PART_W;
        loc[s] = atomicAdd(&cnt8[pb[s]], 1);
    }
    __syncthreads();
    if (t < 8) gbase[t] = atomicAdd(&bcur[t], cnt8[t]);
    if (t == 0) {
        int acc = 0;
#pragma unroll
        for (int q = 0; q < 8; ++q) { offc[q] = acc; acc += cnt8[q]; }
    }
    __syncthreads();
#pragma unroll
    for (int s = 0; s < 3; ++s) {
        int pos = offc[pb[s]] + loc[s];
        spk[pos] = pk[s];
        smeta[pos] = (unsigned short)((s << 13) | (r[s] - pb[s] * PART_W));
    }
    __syncthreads();
#pragma unroll
    for (int k = 0; k < 3; ++k) {
        int i = t + k * 256;
        int q = 0;
#pragma unroll
        for (int b = 1; b < 8; ++b) q += (i >= offc[b]);
        int g = q * BCAP + gbase[q] + (i - offc[q]);
        gpack[g] = spk[i];
        gmeta[g] = smeta[i];
    }
}

// Pass B: partition bucket -> 64 sub-buckets (98-row ranges). blockIdx&7 = p.
__global__ void subbucket_kernel(const unsigned* __restrict__ gpack1,
                                 const unsigned short* __restrict__ gmeta1,
                                 const int* __restrict__ bcur,
                                 int* __restrict__ subcur,
                                 unsigned* __restrict__ gpack2,
                                 unsigned short* __restrict__ gmeta2) {
    int p = blockIdx.x & (NPART - 1);
    int chunk = blockIdx.x >> 3;
    int base = chunk * ENT_B;
    int n = bcur[p];
    int cnt = n - base;
    if (cnt <= 0) return;                // uniform across block
    if (cnt > ENT_B) cnt = ENT_B;
    __shared__ int c64[NSUB];
    __shared__ int off[NSUB];
    __shared__ int gb[NSUB];
    __shared__ unsigned spk[ENT_B];
    __shared__ unsigned short smt[ENT_B];
    int t = threadIdx.x;
    if (t < NSUB) c64[t] = 0;
    __syncthreads();
    unsigned pk[16]; unsigned short mt[16]; int loc[16]; int sb[16];
#pragma unroll
    for (int k = 0; k < 16; ++k) {
        int i = t + k * 256;
        if (i < cnt) {
            pk[k] = gpack1[p * BCAP + base + i];
            mt[k] = gmeta1[p * BCAP + base + i];
            sb[k] = (int)(mt[k] & 8191u) / SUBW;
            loc[k] = atomicAdd(&c64[sb[k]], 1);
        } else sb[k] = -1;
    }
    __syncthreads();
    if (t == 0) {
        int a = 0;
#pragma unroll
        for (int q = 0; q < NSUB; ++q) { off[q] = a; a += c64[q]; }
    }
    __syncthreads();
    if (t < NSUB && c64[t] > 0) gb[t] = atomicAdd(&subcur[p * NSUB + t], c64[t]);
    __syncthreads();
#pragma unroll
    for (int k = 0; k < 16; ++k) {
        if (sb[k] >= 0) {
            int pos = off[sb[k]] + loc[k];
            spk[pos] = pk[k];
            smt[pos] = mt[k];
        }
    }
    __syncthreads();
    for (int i = t; i < cnt; i += 256) {
        unsigned short m = smt[i];
        int s2 = (int)(m & 8191u) / SUBW;
        int g = (p * NSUB + s2) * SUBCAP + gb[s2] + (i - off[s2]);
        gpack2[g] = spk[i];
        gmeta2[g] = m;
    }
}

// Pass C: LDS counting sort of one sub-bucket; block reserves per-segment
// output ranges (atomic cursors) and emits starts+rowlen.
// spack layout: seg s occupies [s*NNZ, (s+1)*NNZ).
__global__ __launch_bounds__(512) void sort_write_kernel(
        const unsigned* __restrict__ gpack2,
        const unsigned short* __restrict__ gmeta2,
        const int* __restrict__ subcur,
        int* __restrict__ cur3,
        int* __restrict__ starts,
        int* __restrict__ rowlen,
        unsigned* __restrict__ spack) {
    int p = blockIdx.x & (NPART - 1);
    int sub = blockIdx.x >> 3;
    int n = subcur[p * NSUB + sub];
    __shared__ int h[512];
    __shared__ int e[512];
    __shared__ int cur[512];
    __shared__ int segbase[4];           // [0]=0 .. [3]=n
    __shared__ int gbs[3];               // per-segment global (within-seg) base
    __shared__ unsigned sorted[SUBCAP];
    int t = threadIdx.x;
    h[t] = 0;
    __syncthreads();
    long base = (long)(p * NSUB + sub) * SUBCAP;
    unsigned pk[12]; short ky[12];
#pragma unroll
    for (int k = 0; k < 12; ++k) {           // SUBCAP = 12*512 exactly
        int i = t + k * 512;
        if (i < n) {
            pk[k] = gpack2[base + i];
            unsigned short m = gmeta2[base + i];
            int key = (int)(m >> 13) * SUBW + ((int)(m & 8191u) - sub * SUBW);
            ky[k] = (short)key;
            atomicAdd(&h[key], 1);
        } else ky[k] = -1;
    }
    __syncthreads();
    e[t] = h[t];
    __syncthreads();
    for (int off = 1; off < 512; off <<= 1) {
        int v = (t >= off) ? e[t - off] : 0;
        __syncthreads();
        e[t] += v;
        __syncthreads();
    }
    int excl = e[t] - h[t];
    __syncthreads();
    e[t] = excl;
    cur[t] = excl;
    __syncthreads();
    if (t == 0) {
        segbase[0] = 0;
        segbase[1] = e[SUBW];
        segbase[2] = e[2 * SUBW];
        segbase[3] = n;
    }
    __syncthreads();
    if (t < 3) gbs[t] = atomicAdd(&cur3[t], segbase[t + 1] - segbase[t]);
    // LDS scatter (concurrent with the t<3 reservations; disjoint memory)
#pragma unroll
    for (int k = 0; k < 12; ++k) {
        if (ky[k] >= 0) {
            int pos = atomicAdd(&cur[ky[k]], 1);
            sorted[pos] = pk[k];
        }
    }
    __syncthreads();
    // Emit row pointers + lengths for this block's 98 rows x 3 segments.
    if (t < 3 * SUBW) {
        int s = t / SUBW, d = t - s * SUBW;
        int rl = sub * SUBW + d;
        if (rl < PART_W) {
            int gr = s * N_NODES + p * PART_W + rl;
            starts[gr] = s * NNZ + gbs[s] + (e[t] - segbase[s]);
            rowlen[gr] = h[t];
        }
    }
    // Coalesced contiguous entry write-out (one chunk per segment).
    int s1 = segbase[1], s2 = segbase[2];
#pragma unroll
    for (int k = 0; k < 12; ++k) {
        int i = t + k * 512;
        if (i < n) {
            int sg = (i < s1) ? 0 : ((i < s2) ? 1 : 2);
            spack[sg * NNZ + gbs[sg] + (i - segbase[sg])] = sorted[i];
        }
    }
}

// -----------------------------------------------------------------------------
// Phase 1: per-row gather  xw{1,2}[r,:] = sum_e v_e * W{1,2}[c_e,:]
// fp16 interleaved table: ONE uint4 (16 B) load per edge covers BOTH tables.
// Output in 32-dim-slice layout: xw[s][r][d32], s in [0,4), 64 B per row-slice.
// -----------------------------------------------------------------------------
__global__ void feat_gather_kernel(const int* __restrict__ starts,
                                   const int* __restrict__ rowlen,
                                   const unsigned* __restrict__ spack,
                                   const uint4* __restrict__ Wc,
                                   ushort4* __restrict__ xw1s,
                                   ushort4* __restrict__ xw2s) {
    int lane = threadIdx.x & 31;
    int sub  = threadIdx.x >> 5;
    int r = blockIdx.x * 8 + sub;
    if (r >= N_NODES) return;
    int s = starts[r];
    int e = s + rowlen[r];
    float4 a1 = make_float4(0.f, 0.f, 0.f, 0.f);
    float4 a2 = make_float4(0.f, 0.f, 0.f, 0.f);
    for (int base = s; base < e; base += 32) {
        int n = e - base;
        int m = (n < 32) ? n : 32;
        unsigned pk = (lane < m) ? spack[base + lane] : 0u;
        int j = 0;
        for (; j + 7 < m; j += 8) {
            unsigned pp[8]; uint4 wv[8];
#pragma unroll
            for (int k = 0; k < 8; ++k) pp[k] = __shfl(pk, j + k, 32);
#pragma unroll
            for (int k = 0; k < 8; ++k) wv[k] = Wc[upk_c(pp[k]) * 32 + lane];
#pragma unroll
            for (int k = 0; k < 8; ++k) {
                float v = upk_v(pp[k]);
                a1.x += v * h2f((unsigned short)(wv[k].x & 0xffffu));
                a1.y += v * h2f((unsigned short)(wv[k].x >> 16));
                a1.z += v * h2f((unsigned short)(wv[k].y & 0xffffu));
                a1.w += v * h2f((unsigned short)(wv[k].y >> 16));
                a2.x += v * h2f((unsigned short)(wv[k].z & 0xffffu));
                a2.y += v * h2f((unsigned short)(wv[k].z >> 16));
                a2.z += v * h2f((unsigned short)(wv[k].w & 0xffffu));
                a2.w += v * h2f((unsigned short)(wv[k].w >> 16));
            }
        }
        for (; j < m; ++j) {
            unsigned pj = __shfl(pk, j, 32);
            float v = upk_v(pj);
            uint4 wv = Wc[upk_c(pj) * 32 + lane];
            a1.x += v * h2f((unsigned short)(wv.x & 0xffffu));
            a1.y += v * h2f((unsigned short)(wv.x >> 16));
            a1.z += v * h2f((unsigned short)(wv.y & 0xffffu));
            a1.w += v * h2f((unsigned short)(wv.y >> 16));
            a2.x += v * h2f((unsigned short)(wv.z & 0xffffu));
            a2.y += v * h2f((unsigned short)(wv.z >> 16));
            a2.z += v * h2f((unsigned short)(wv.w & 0xffffu));
            a2.w += v * h2f((unsigned short)(wv.w >> 16));
        }
    }
    ushort4 q1, q2;
    q1.x = __half_as_ushort(__float2half(a1.x)); q1.y = __half_as_ushort(__float2half(a1.y));
    q1.z = __half_as_ushort(__float2half(a1.z)); q1.w = __half_as_ushort(__float2half(a1.w));
    q2.x = __half_as_ushort(__float2half(a2.x)); q2.y = __half_as_ushort(__float2half(a2.y));
    q2.z = __half_as_ushort(__float2half(a2.z)); q2.w = __half_as_ushort(__float2half(a2.w));
    // 32-dim-slice store: lanes {8k..8k+7} write one full 64 B line.
    size_t idx = (size_t)(lane >> 3) * (N_NODES * 8) + (size_t)r * 8 + (lane & 7);
    xw1s[idx] = q1;
    xw2s[idx] = q2;
}

// -----------------------------------------------------------------------------
// Phase 2, FUSED: out[r, 32s:32s+32] = relu( sum_adj1 v*xw1[s][c][:]
//                                          + sum_adj2 v*xw2[s][c][:] ).
// One dispatch (>50 us -> surfaces in rocprof top-5 with counters — this
// round's measurement goal). Per-phase the block touches ONE 3.2 MB slice;
// phases are temporally separated per block, so L2 residency should mostly
// hold (FETCH_SIZE is the verdict). Also removes the 25 MB out write +
// 25 MB read-back of the old two-pass scheme.
// -----------------------------------------------------------------------------
__global__ __launch_bounds__(512) void adj_pass_fused(
        const int* __restrict__ starts,
        const int* __restrict__ rowlen,
        const unsigned* __restrict__ spack,
        const ushort4* __restrict__ xw1s,
        const ushort4* __restrict__ xw2s,
        vf4* __restrict__ out) {
    int s  = blockIdx.x & (ADJ_SL - 1);
    int rc = blockIdx.x >> 2;
    int g  = threadIdx.x >> 3;          // 64 row-groups per block
    int q  = threadIdx.x & 7;
    int r  = rc * 64 + g;
    bool valid = (r < N_NODES);
    vf4 acc = {0.f, 0.f, 0.f, 0.f};

#pragma unroll
    for (int rel = 0; rel < 2; ++rel) {
        const ushort4* __restrict__ sl =
            ((rel == 0) ? xw1s : xw2s) + (size_t)s * (N_NODES * 8);
        int st = 0, en = 0;
        if (valid) {
            st = starts[(1 + rel) * N_NODES + r];
            en = st + rowlen[(1 + rel) * N_NODES + r];
        }
        for (int base = st; base < en; base += 16) {
            int m = en - base;
            unsigned pk0 = (q < m)     ? spack[base + q]     : 0u;
            unsigned pk1 = (8 + q < m) ? spack[base + 8 + q] : 0u;
            {
                unsigned pp[8]; ushort4 xx[8];
#pragma unroll
                for (int k = 0; k < 8; ++k) pp[k] = __shfl(pk0, k, 8);
#pragma unroll
                for (int k = 0; k < 8; ++k) xx[k] = sl[upk_c(pp[k]) * 8 + q];
#pragma unroll
                for (int k = 0; k < 8; ++k) {
                    float v = upk_v(pp[k]);
                    acc.x += v * h2f(xx[k].x); acc.y += v * h2f(xx[k].y);
                    acc.z += v * h2f(xx[k].z); acc.w += v * h2f(xx[k].w);
                }
            }
            if (m <= 8) continue;
            {
                unsigned pp[8]; ushort4 xx[8];
#pragma unroll
                for (int k = 0; k < 8; ++k) pp[k] = __shfl(pk1, k, 8);
#pragma unroll
                for (int k = 0; k < 8; ++k) xx[k] = sl[upk_c(pp[k]) * 8 + q];
#pragma unroll
                for (int k = 0; k < 8; ++k) {
                    float v = upk_v(pp[k]);
                    acc.x += v * h2f(xx[k].x); acc.y += v * h2f(xx[k].y);
                    acc.z += v * h2f(xx[k].z); acc.w += v * h2f(xx[k].w);
                }
            }
        }
    }
    if (valid) {
        vf4 res;
        res.x = fmaxf(acc.x, 0.f);
        res.y = fmaxf(acc.y, 0.f);
        res.z = fmaxf(acc.z, 0.f);
        res.w = fmaxf(acc.w, 0.f);
        __builtin_nontemporal_store(res, &out[(size_t)r * 32 + s * 8 + q]);
    }
}

extern "C" void kernel_launch(void* const* d_in, const int* in_sizes, int n_in,
                              void* d_out, int out_size, void* d_ws, size_t ws_size,
                              hipStream_t stream) {
    const int*   feat_row  = (const int*)  d_in[0];
    const int*   feat_col  = (const int*)  d_in[1];
    const float* feat_vals = (const float*)d_in[2];
    const int*   adj1_row  = (const int*)  d_in[3];
    const int*   adj1_col  = (const int*)  d_in[4];
    const float* adj1_vals = (const float*)d_in[5];
    const int*   adj2_row  = (const int*)  d_in[6];
    const int*   adj2_col  = (const int*)  d_in[7];
    const float* adj2_vals = (const float*)d_in[8];
    const float* W1        = (const float*)d_in[9];
    const float* W2        = (const float*)d_in[10];

    // Workspace layout. Bucket storage (~33.8 MB) is dead after sort_write,
    // so xw1s/xw2s (25.6 MB) alias it. Total footprint ~45 MB.
    char* ws = (char*)d_ws;
    unsigned* spack = (unsigned*)ws;            ws += (size_t)TOTAL_NNZ * 4;          // 9.6 MB
    int*      starts= (int*)ws;                 ws += (size_t)SCAN_N * 4;             // 600 KB
    int*      rowlen= (int*)ws;                 ws += (size_t)SCAN_N * 4;             // 600 KB
    int*      bcur  = (int*)ws;                 ws += 16 * 4;                         // 8 used
    int*      subcur= (int*)ws;                 ws += (size_t)NPART * NSUB * 4;       // 2 KB
    int*      cur3  = (int*)ws;                 ws += 16 * 4;                         // 3 used
    uint4*    Wc    = (uint4*)ws;               ws += (size_t)256 * 32 * 16;          // 128 KB
    char*     bkt   = ws;                                                             // bucket region
    unsigned* gpack1 = (unsigned*)bkt;
    unsigned short* gmeta1 = (unsigned short*)(bkt + (size_t)NPART * BCAP * 4);
    unsigned* gpack2 = (unsigned*)(bkt + (size_t)NPART * BCAP * 6);
    unsigned short* gmeta2 = (unsigned short*)(bkt + (size_t)NPART * BCAP * 6
                                                  + (size_t)NPART * NSUB * SUBCAP * 4);
    ushort4*  xw1s  = (ushort4*)bkt;                                     // alias (after C)
    ushort4*  xw2s  = (ushort4*)(bkt + (size_t)N_NODES * OUT_DIM * 2);   // alias

    // Zero cursors: bcur(16) + subcur(512) + cur3(16), contiguous.
    (void)hipMemsetAsync(bcur, 0, (16 + NPART * NSUB + 16) * sizeof(int), stream);

    const int block = 256;

    // W prep: interleaved fp16 table (independent of the sort).
    wprep_kernel<<<32, block, 0, stream>>>(W1, W2, Wc);

    // A: single read of all 9 streams, LDS-bucket by row partition.
    bucket_kernel<<<NNZ / block, block, 0, stream>>>(
        feat_row, feat_col, feat_vals,
        adj1_row, adj1_col, adj1_vals,
        adj2_row, adj2_col, adj2_vals,
        bcur, gpack1, gmeta1);

    // B: partition bucket -> 64 sub-buckets (XCD-local reads, blockIdx&7 = p).
    subbucket_kernel<<<NPART * BBLK_B, block, 0, stream>>>(
        gpack1, gmeta1, bcur, subcur, gpack2, gmeta2);

    // C: LDS counting sort per sub-bucket; self-allocated output ranges,
    // emits starts+rowlen directly (no global histogram/scan kernels).
    sort_write_kernel<<<NPART * NSUB, 512, 0, stream>>>(
        gpack2, gmeta2, subcur, cur3, starts, rowlen, spack);

    const int grid_rows = N_NODES / 8;                           // 6250 blocks, 8 rows each
    feat_gather_kernel<<<grid_rows, 256, 0, stream>>>(
        starts, rowlen, spack, Wc, xw1s, xw2s);

    // Phase 2: FUSED rel0+rel1, 32-dim slices, full-line gathers.
    adj_pass_fused<<<ADJ_SL * ADJ_RC, 512, 0, stream>>>(
        starts, rowlen, spack, xw1s, xw2s, (vf4*)d_out);
}

// Round 16
// 223.822 us; speedup vs baseline: 1.4054x; 1.1214x over previous
//
#include <hip/hip_runtime.h>
#include <hip/hip_fp16.h>

// Problem constants (fixed by the reference setup)
#define N_NODES 50000
#define IN_DIM 256
#define OUT_DIM 128
#define NNZ 800000          // nnz for feat, adj1, adj2 each
#define SCAN_N (3 * N_NODES)        // 150000 row pointers (feat | adj1 | adj2)
#define TOTAL_NNZ (3 * NNZ)         // 2.4M sorted entries

// Sub-buckets: 98-row ranges, 511 of them (511*98 = 50078 >= 50000).
// Expected entries/bucket = 2.4M*98/50000 = 4704, sigma ~68.
// SUBCAP 6144 = mean + 21 sigma (populations identical to rounds 2..15 -> HW-validated).
#define NSB 511
#define SUBW 98
#define SUBCAP 6144

// superbucket: 512 threads, 1024 edges/block -> 3072 entries staged in 24 KB.
// LDS total ~30 KB (stage 24K + 3x2K counters). Atomics: 3072 over 512
// counters = ~6/counter (vs 96/counter in the old 8-way level-1 pass).
#define EB 1024
#define SB_GRID ((NNZ + EB - 1) / EB)   // 782

// adj phase: ONE fused dispatch (rel0 then rel1 per row); 32-dim slices.
// Round-15 measured: 63 us, VALU-bound (not BW-bound despite FETCH 169 MB).
#define ADJ_SL 4
#define ADJ_RC ((N_NODES + 63) / 64)  // 782 row-chunks of 64 rows

// Native clang vector types.
typedef float vf4 __attribute__((ext_vector_type(4)));

// Packed entry: [col:16 | fp16(val):16].  adj cols < 50000 < 65536, feat cols < 256.
static __device__ __forceinline__ unsigned pack_cv(int c, float v) {
    return ((unsigned)c << 16) | (unsigned)__half_as_ushort(__float2half(v));
}
static __device__ __forceinline__ int   upk_c(unsigned pk) { return (int)(pk >> 16); }
static __device__ __forceinline__ float upk_v(unsigned pk) {
    return __half2float(__ushort_as_half((unsigned short)(pk & 0xffffu)));
}
static __device__ __forceinline__ float h2f(unsigned short h) {
    return __half2float(__ushort_as_half(h));
}
static __device__ __forceinline__ unsigned pk2h(float x, float y) {
    return (unsigned)__half_as_ushort(__float2half(x))
         | ((unsigned)__half_as_ushort(__float2half(y)) << 16);
}

// -----------------------------------------------------------------------------
// wprep: interleave W1|W2 into ONE fp16 table (cache-resident, 128 KB).
// -----------------------------------------------------------------------------
__global__ void wprep_kernel(const float* __restrict__ W1,
                             const float* __restrict__ W2,
                             uint4* __restrict__ Wc) {
    int idx = blockIdx.x * 256 + threadIdx.x;   // 8192 = 256 rows * 32 lanes
    const float4* w1 = (const float4*)W1;
    const float4* w2 = (const float4*)W2;
    float4 a = w1[idx];
    float4 b = w2[idx];
    uint4 o;
    o.x = pk2h(a.x, a.y);
    o.y = pk2h(a.z, a.w);
    o.z = pk2h(b.x, b.y);
    o.w = pk2h(b.z, b.w);
    Wc[idx] = o;
}

// -----------------------------------------------------------------------------
// CSR build, TWO kernels (was three):
//   A (superbucket_kernel): read every edge ONCE, LDS-group 3072 entries
//     DIRECTLY by final 98-row bucket (row/98, 511 buckets), append ~6-entry
//     chunks to per-bucket global storage. Removes a full 2.4M-entry pass
//     and the 96-way LDS-atomic serialization of the old level-1.
//     Entry = u64 [sb:16|key:16|pack:32], key = seg*98 + row%98 in [0,294).
//   B (sort_write_kernel): per-bucket LDS counting sort; block RESERVES its
//     per-segment output ranges via 3 atomic cursors and emits starts[r] +
//     rowlen[r] itself (round-11-validated; no global scan kernels).
// -----------------------------------------------------------------------------
__global__ __launch_bounds__(512) void superbucket_kernel(
        const int* __restrict__ fr, const int* __restrict__ fc,
        const float* __restrict__ fv,
        const int* __restrict__ a1r, const int* __restrict__ a1c,
        const float* __restrict__ a1v,
        const int* __restrict__ a2r, const int* __restrict__ a2c,
        const float* __restrict__ a2v,
        int* __restrict__ subcur,
        unsigned* __restrict__ gpack2,
        unsigned short* __restrict__ gmeta2) {
    __shared__ unsigned long long stage[3 * EB];   // 24 KB
    __shared__ int c512[512];                      // +2 KB
    __shared__ int offE[512];                      // +2 KB
    __shared__ int gb[512];                        // +2 KB
    int t = threadIdx.x;
    c512[t] = 0;
    __syncthreads();
    int base = blockIdx.x * EB;
    int nE = NNZ - base; if (nE > EB) nE = EB;
    int tot = 3 * nE;

    unsigned long long ent[6]; int sbA[6]; int loc[6];
#pragma unroll
    for (int k = 0; k < 2; ++k) {
        int i = k * 512 + t;
        int e = base + i;
        if (i < nE) {
            int r0 = __builtin_nontemporal_load(&fr[e]);
            unsigned p0 = pack_cv(__builtin_nontemporal_load(&fc[e]),
                                  __builtin_nontemporal_load(&fv[e]));
            int s0 = r0 / SUBW;
            ent[3*k]   = ((unsigned long long)s0 << 48)
                       | ((unsigned long long)(r0 - s0 * SUBW) << 32) | p0;
            sbA[3*k] = s0;  loc[3*k] = atomicAdd(&c512[s0], 1);

            int r1 = __builtin_nontemporal_load(&a1r[e]);
            unsigned p1 = pack_cv(__builtin_nontemporal_load(&a1c[e]),
                                  __builtin_nontemporal_load(&a1v[e]));
            int s1 = r1 / SUBW;
            ent[3*k+1] = ((unsigned long long)s1 << 48)
                       | ((unsigned long long)(SUBW + r1 - s1 * SUBW) << 32) | p1;
            sbA[3*k+1] = s1;  loc[3*k+1] = atomicAdd(&c512[s1], 1);

            int r2 = __builtin_nontemporal_load(&a2r[e]);
            unsigned p2 = pack_cv(__builtin_nontemporal_load(&a2c[e]),
                                  __builtin_nontemporal_load(&a2v[e]));
            int s2 = r2 / SUBW;
            ent[3*k+2] = ((unsigned long long)s2 << 48)
                       | ((unsigned long long)(2 * SUBW + r2 - s2 * SUBW) << 32) | p2;
            sbA[3*k+2] = s2;  loc[3*k+2] = atomicAdd(&c512[s2], 1);
        } else {
            sbA[3*k] = sbA[3*k+1] = sbA[3*k+2] = -1;
        }
    }
    __syncthreads();
    // Hillis-Steele inclusive scan over the 512 bucket counts.
    offE[t] = c512[t];
    __syncthreads();
    for (int off = 1; off < 512; off <<= 1) {
        int v = (t >= off) ? offE[t - off] : 0;
        __syncthreads();
        offE[t] += v;
        __syncthreads();
    }
    int excl = offE[t] - c512[t];
    __syncthreads();
    offE[t] = excl;
    if (c512[t] > 0) gb[t] = atomicAdd(&subcur[t], c512[t]);
    __syncthreads();
#pragma unroll
    for (int k = 0; k < 6; ++k) {
        if (sbA[k] >= 0) stage[offE[sbA[k]] + loc[k]] = ent[k];
    }
    __syncthreads();
    // Write-out: ~6-entry contiguous chunks per bucket.
    for (int i = t; i < tot; i += 512) {
        unsigned long long v = stage[i];
        int sb = (int)(v >> 48);
        int g = sb * SUBCAP + gb[sb] + (i - offE[sb]);
        gpack2[g] = (unsigned)v;
        gmeta2[g] = (unsigned short)(v >> 32);   // key in [0,294)
    }
}

// Pass B: LDS counting sort of one sub-bucket; block reserves per-segment
// output ranges (atomic cursors) and emits starts+rowlen.
// spack layout: seg s occupies [s*NNZ, (s+1)*NNZ).
__global__ __launch_bounds__(512) void sort_write_kernel(
        const unsigned* __restrict__ gpack2,
        const unsigned short* __restrict__ gmeta2,
        const int* __restrict__ subcur,
        int* __restrict__ cur3,
        int* __restrict__ starts,
        int* __restrict__ rowlen,
        unsigned* __restrict__ spack) {
    int sb = blockIdx.x;                 // 0..510
    int n = subcur[sb];
    __shared__ int h[512];
    __shared__ int e[512];
    __shared__ int cur[512];
    __shared__ int segbase[4];           // [0]=0 .. [3]=n
    __shared__ int gbs[3];               // per-segment global (within-seg) base
    __shared__ unsigned sorted[SUBCAP];
    int t = threadIdx.x;
    h[t] = 0;
    __syncthreads();
    long base = (long)sb * SUBCAP;
    unsigned pk[12]; short ky[12];
#pragma unroll
    for (int k = 0; k < 12; ++k) {           // SUBCAP = 12*512 exactly
        int i = t + k * 512;
        if (i < n) {
            pk[k] = gpack2[base + i];
            ky[k] = (short)gmeta2[base + i]; // key in [0,294)
            atomicAdd(&h[ky[k]], 1);
        } else ky[k] = -1;
    }
    __syncthreads();
    e[t] = h[t];
    __syncthreads();
    for (int off = 1; off < 512; off <<= 1) {
        int v = (t >= off) ? e[t - off] : 0;
        __syncthreads();
        e[t] += v;
        __syncthreads();
    }
    int excl = e[t] - h[t];
    __syncthreads();
    e[t] = excl;
    cur[t] = excl;
    __syncthreads();
    if (t == 0) {
        segbase[0] = 0;
        segbase[1] = e[SUBW];
        segbase[2] = e[2 * SUBW];
        segbase[3] = n;
    }
    __syncthreads();
    if (t < 3) gbs[t] = atomicAdd(&cur3[t], segbase[t + 1] - segbase[t]);
    // LDS scatter (concurrent with the t<3 reservations; disjoint memory)
#pragma unroll
    for (int k = 0; k < 12; ++k) {
        if (ky[k] >= 0) {
            int pos = atomicAdd(&cur[ky[k]], 1);
            sorted[pos] = pk[k];
        }
    }
    __syncthreads();
    // Emit row pointers + lengths for this block's 98 rows x 3 segments.
    if (t < 3 * SUBW) {
        int s = t / SUBW, d = t - s * SUBW;
        int r = sb * SUBW + d;
        if (r < N_NODES) {
            int gr = s * N_NODES + r;
            starts[gr] = s * NNZ + gbs[s] + (e[t] - segbase[s]);
            rowlen[gr] = h[t];
        }
    }
    // Coalesced contiguous entry write-out (one chunk per segment).
    int s1 = segbase[1], s2 = segbase[2];
#pragma unroll
    for (int k = 0; k < 12; ++k) {
        int i = t + k * 512;
        if (i < n) {
            int sg = (i < s1) ? 0 : ((i < s2) ? 1 : 2);
            spack[sg * NNZ + gbs[sg] + (i - segbase[sg])] = sorted[i];
        }
    }
}

// -----------------------------------------------------------------------------
// Phase 1: per-row gather  xw{1,2}[r,:] = sum_e v_e * W{1,2}[c_e,:]
// fp16 interleaved table: ONE uint4 (16 B) load per edge covers BOTH tables.
// Output in 32-dim-slice layout: xw[s][r][d32], s in [0,4), 64 B per row-slice.
// -----------------------------------------------------------------------------
__global__ void feat_gather_kernel(const int* __restrict__ starts,
                                   const int* __restrict__ rowlen,
                                   const unsigned* __restrict__ spack,
                                   const uint4* __restrict__ Wc,
                                   ushort4* __restrict__ xw1s,
                                   ushort4* __restrict__ xw2s) {
    int lane = threadIdx.x & 31;
    int sub  = threadIdx.x >> 5;
    int r = blockIdx.x * 8 + sub;
    if (r >= N_NODES) return;
    int s = starts[r];
    int e = s + rowlen[r];
    float4 a1 = make_float4(0.f, 0.f, 0.f, 0.f);
    float4 a2 = make_float4(0.f, 0.f, 0.f, 0.f);
    for (int base = s; base < e; base += 32) {
        int n = e - base;
        int m = (n < 32) ? n : 32;
        unsigned pk = (lane < m) ? spack[base + lane] : 0u;
        int j = 0;
        for (; j + 7 < m; j += 8) {
            unsigned pp[8]; uint4 wv[8];
#pragma unroll
            for (int k = 0; k < 8; ++k) pp[k] = __shfl(pk, j + k, 32);
#pragma unroll
            for (int k = 0; k < 8; ++k) wv[k] = Wc[upk_c(pp[k]) * 32 + lane];
#pragma unroll
            for (int k = 0; k < 8; ++k) {
                float v = upk_v(pp[k]);
                a1.x += v * h2f((unsigned short)(wv[k].x & 0xffffu));
                a1.y += v * h2f((unsigned short)(wv[k].x >> 16));
                a1.z += v * h2f((unsigned short)(wv[k].y & 0xffffu));
                a1.w += v * h2f((unsigned short)(wv[k].y >> 16));
                a2.x += v * h2f((unsigned short)(wv[k].z & 0xffffu));
                a2.y += v * h2f((unsigned short)(wv[k].z >> 16));
                a2.z += v * h2f((unsigned short)(wv[k].w & 0xffffu));
                a2.w += v * h2f((unsigned short)(wv[k].w >> 16));
            }
        }
        for (; j < m; ++j) {
            unsigned pj = __shfl(pk, j, 32);
            float v = upk_v(pj);
            uint4 wv = Wc[upk_c(pj) * 32 + lane];
            a1.x += v * h2f((unsigned short)(wv.x & 0xffffu));
            a1.y += v * h2f((unsigned short)(wv.x >> 16));
            a1.z += v * h2f((unsigned short)(wv.y & 0xffffu));
            a1.w += v * h2f((unsigned short)(wv.y >> 16));
            a2.x += v * h2f((unsigned short)(wv.z & 0xffffu));
            a2.y += v * h2f((unsigned short)(wv.z >> 16));
            a2.z += v * h2f((unsigned short)(wv.w & 0xffffu));
            a2.w += v * h2f((unsigned short)(wv.w >> 16));
        }
    }
    ushort4 q1, q2;
    q1.x = __half_as_ushort(__float2half(a1.x)); q1.y = __half_as_ushort(__float2half(a1.y));
    q1.z = __half_as_ushort(__float2half(a1.z)); q1.w = __half_as_ushort(__float2half(a1.w));
    q2.x = __half_as_ushort(__float2half(a2.x)); q2.y = __half_as_ushort(__float2half(a2.y));
    q2.z = __half_as_ushort(__float2half(a2.z)); q2.w = __half_as_ushort(__float2half(a2.w));
    // 32-dim-slice store: lanes {8k..8k+7} write one full 64 B line.
    size_t idx = (size_t)(lane >> 3) * (N_NODES * 8) + (size_t)r * 8 + (lane & 7);
    xw1s[idx] = q1;
    xw2s[idx] = q2;
}

// -----------------------------------------------------------------------------
// Phase 2, FUSED (round-15 measured: 63 us, VALU-bound, keep):
//   out[r, 32s:32s+32] = relu( sum_adj1 v*xw1[s][c][:] + sum_adj2 v*xw2[s][c][:] )
// -----------------------------------------------------------------------------
__global__ __launch_bounds__(512) void adj_pass_fused(
        const int* __restrict__ starts,
        const int* __restrict__ rowlen,
        const unsigned* __restrict__ spack,
        const ushort4* __restrict__ xw1s,
        const ushort4* __restrict__ xw2s,
        vf4* __restrict__ out) {
    int s  = blockIdx.x & (ADJ_SL - 1);
    int rc = blockIdx.x >> 2;
    int g  = threadIdx.x >> 3;          // 64 row-groups per block
    int q  = threadIdx.x & 7;
    int r  = rc * 64 + g;
    bool valid = (r < N_NODES);
    vf4 acc = {0.f, 0.f, 0.f, 0.f};

#pragma unroll
    for (int rel = 0; rel < 2; ++rel) {
        const ushort4* __restrict__ sl =
            ((rel == 0) ? xw1s : xw2s) + (size_t)s * (N_NODES * 8);
        int st = 0, en = 0;
        if (valid) {
            st = starts[(1 + rel) * N_NODES + r];
            en = st + rowlen[(1 + rel) * N_NODES + r];
        }
        for (int base = st; base < en; base += 16) {
            int m = en - base;
            unsigned pk0 = (q < m)     ? spack[base + q]     : 0u;
            unsigned pk1 = (8 + q < m) ? spack[base + 8 + q] : 0u;
            {
                unsigned pp[8]; ushort4 xx[8];
#pragma unroll
                for (int k = 0; k < 8; ++k) pp[k] = __shfl(pk0, k, 8);
#pragma unroll
                for (int k = 0; k < 8; ++k) xx[k] = sl[upk_c(pp[k]) * 8 + q];
#pragma unroll
                for (int k = 0; k < 8; ++k) {
                    float v = upk_v(pp[k]);
                    acc.x += v * h2f(xx[k].x); acc.y += v * h2f(xx[k].y);
                    acc.z += v * h2f(xx[k].z); acc.w += v * h2f(xx[k].w);
                }
            }
            if (m <= 8) continue;
            {
                unsigned pp[8]; ushort4 xx[8];
#pragma unroll
                for (int k = 0; k < 8; ++k) pp[k] = __shfl(pk1, k, 8);
#pragma unroll
                for (int k = 0; k < 8; ++k) xx[k] = sl[upk_c(pp[k]) * 8 + q];
#pragma unroll
                for (int k = 0; k < 8; ++k) {
                    float v = upk_v(pp[k]);
                    acc.x += v * h2f(xx[k].x); acc.y += v * h2f(xx[k].y);
                    acc.z += v * h2f(xx[k].z); acc.w += v * h2f(xx[k].w);
                }
            }
        }
    }
    if (valid) {
        vf4 res;
        res.x = fmaxf(acc.x, 0.f);
        res.y = fmaxf(acc.y, 0.f);
        res.z = fmaxf(acc.z, 0.f);
        res.w = fmaxf(acc.w, 0.f);
        __builtin_nontemporal_store(res, &out[(size_t)r * 32 + s * 8 + q]);
    }
}

extern "C" void kernel_launch(void* const* d_in, const int* in_sizes, int n_in,
                              void* d_out, int out_size, void* d_ws, size_t ws_size,
                              hipStream_t stream) {
    const int*   feat_row  = (const int*)  d_in[0];
    const int*   feat_col  = (const int*)  d_in[1];
    const float* feat_vals = (const float*)d_in[2];
    const int*   adj1_row  = (const int*)  d_in[3];
    const int*   adj1_col  = (const int*)  d_in[4];
    const float* adj1_vals = (const float*)d_in[5];
    const int*   adj2_row  = (const int*)  d_in[6];
    const int*   adj2_col  = (const int*)  d_in[7];
    const float* adj2_vals = (const float*)d_in[8];
    const float* W1        = (const float*)d_in[9];
    const float* W2        = (const float*)d_in[10];

    // Workspace layout (~37 MB). Bucket storage (18.9 MB) is dead after
    // sort_write; xw1s/xw2s (25.6 MB) alias over it.
    char* ws = (char*)d_ws;
    unsigned* spack = (unsigned*)ws;            ws += (size_t)TOTAL_NNZ * 4;          // 9.6 MB
    int*      starts= (int*)ws;                 ws += (size_t)SCAN_N * 4;             // 600 KB
    int*      rowlen= (int*)ws;                 ws += (size_t)SCAN_N * 4;             // 600 KB
    int*      subcur= (int*)ws;                 ws += 512 * 4;                        // 511 used
    int*      cur3  = (int*)ws;                 ws += 16 * 4;                         // 3 used
    uint4*    Wc    = (uint4*)ws;               ws += (size_t)256 * 32 * 16;          // 128 KB
    char*     bkt   = ws;                       // bucket region / xw alias
    unsigned* gpack2 = (unsigned*)bkt;                                     // 12.6 MB
    unsigned short* gmeta2 = (unsigned short*)(bkt + (size_t)NSB * SUBCAP * 4); // 6.3 MB
    ushort4*  xw1s  = (ushort4*)bkt;                                     // alias (after B)
    ushort4*  xw2s  = (ushort4*)(bkt + (size_t)N_NODES * OUT_DIM * 2);   // alias

    // Zero cursors: subcur(512) + cur3(16), contiguous.
    (void)hipMemsetAsync(subcur, 0, (512 + 16) * sizeof(int), stream);

    // W prep: interleaved fp16 table (independent of the sort).
    wprep_kernel<<<32, 256, 0, stream>>>(W1, W2, Wc);

    // A: single pass — read all 9 streams once, bucket into 511 sub-buckets.
    superbucket_kernel<<<SB_GRID, 512, 0, stream>>>(
        feat_row, feat_col, feat_vals,
        adj1_row, adj1_col, adj1_vals,
        adj2_row, adj2_col, adj2_vals,
        subcur, gpack2, gmeta2);

    // B: LDS counting sort per sub-bucket; self-allocated output ranges,
    // emits starts+rowlen directly.
    sort_write_kernel<<<NSB, 512, 0, stream>>>(
        gpack2, gmeta2, subcur, cur3, starts, rowlen, spack);

    const int grid_rows = N_NODES / 8;                           // 6250 blocks, 8 rows each
    feat_gather_kernel<<<grid_rows, 256, 0, stream>>>(
        starts, rowlen, spack, Wc, xw1s, xw2s);

    // Phase 2: FUSED rel0+rel1, 32-dim slices.
    adj_pass_fused<<<ADJ_SL * ADJ_RC, 512, 0, stream>>>(
        starts, rowlen, spack, xw1s, xw2s, (vf4*)d_out);
}

// Round 17
// 219.198 us; speedup vs baseline: 1.4351x; 1.0211x over previous
//
#include <hip/hip_runtime.h>
#include <hip/hip_fp16.h>

// Problem constants (fixed by the reference setup)
#define N_NODES 50000
#define IN_DIM 256
#define OUT_DIM 128
#define NNZ 800000          // nnz for feat, adj1, adj2 each
#define SCAN_N (3 * N_NODES)        // 150000 row pointers (feat | adj1 | adj2)
#define TOTAL_NNZ (3 * NNZ)         // 2.4M entries (spack sized for 3 segs; seg0 unused)

// Sub-buckets: 98-row ranges, 511 of them (511*98 = 50078 >= 50000).
// Expected entries/bucket = 2.4M*98/50000 = 4704, sigma ~68.
// SUBCAP 6144 = mean + 21 sigma (populations HW-validated rounds 2..16).
#define NSB 511
#define SUBW 98
#define SUBCAP 6144

// superbucket: 512 threads, 1024 edges/block -> 3072 entries staged in 24 KB.
#define EB 1024
#define SB_GRID ((NNZ + EB - 1) / EB)   // 782

// adj phase: ONE fused dispatch (round-15/16 measured: ~62 us, latency-floor
// at its 4-line/edge request minimum; keep).
#define ADJ_SL 4
#define ADJ_RC ((N_NODES + 63) / 64)  // 782 row-chunks of 64 rows

// Native clang vector types.
typedef float vf4 __attribute__((ext_vector_type(4)));

// Packed entry: [col:16 | fp16(val):16].  adj cols < 50000 < 65536, feat cols < 256.
static __device__ __forceinline__ unsigned pack_cv(int c, float v) {
    return ((unsigned)c << 16) | (unsigned)__half_as_ushort(__float2half(v));
}
static __device__ __forceinline__ int   upk_c(unsigned pk) { return (int)(pk >> 16); }
static __device__ __forceinline__ float upk_v(unsigned pk) {
    return __half2float(__ushort_as_half((unsigned short)(pk & 0xffffu)));
}
static __device__ __forceinline__ float h2f(unsigned short h) {
    return __half2float(__ushort_as_half(h));
}
static __device__ __forceinline__ unsigned pk2h(float x, float y) {
    return (unsigned)__half_as_ushort(__float2half(x))
         | ((unsigned)__half_as_ushort(__float2half(y)) << 16);
}

// -----------------------------------------------------------------------------
// wprep: interleave W1|W2 into ONE fp16 table (cache-resident, 128 KB).
// Wc[c*32 + l] (uint4) = { w1[c, 4l..4l+3], w2[c, 4l..4l+3] } as 8 halves.
// -----------------------------------------------------------------------------
__global__ void wprep_kernel(const float* __restrict__ W1,
                             const float* __restrict__ W2,
                             uint4* __restrict__ Wc) {
    int idx = blockIdx.x * 256 + threadIdx.x;   // 8192 = 256 rows * 32 lanes
    const float4* w1 = (const float4*)W1;
    const float4* w2 = (const float4*)W2;
    float4 a = w1[idx];
    float4 b = w2[idx];
    uint4 o;
    o.x = pk2h(a.x, a.y);
    o.y = pk2h(a.z, a.w);
    o.z = pk2h(b.x, b.y);
    o.w = pk2h(b.z, b.w);
    Wc[idx] = o;
}

// -----------------------------------------------------------------------------
// A (superbucket_kernel): read every edge ONCE, LDS-group 3072 entries by final
// 98-row bucket (row/98, 511 buckets), append ~6-entry chunks to per-bucket
// storage. Entry = u64 [sb:16|key:16|pack:32], key = seg*98 + row%98 in [0,294).
// (Round-16 validated: replaced the two-level pass, -27 us.)
// -----------------------------------------------------------------------------
__global__ __launch_bounds__(512) void superbucket_kernel(
        const int* __restrict__ fr, const int* __restrict__ fc,
        const float* __restrict__ fv,
        const int* __restrict__ a1r, const int* __restrict__ a1c,
        const float* __restrict__ a1v,
        const int* __restrict__ a2r, const int* __restrict__ a2c,
        const float* __restrict__ a2v,
        int* __restrict__ subcur,
        unsigned* __restrict__ gpack2,
        unsigned short* __restrict__ gmeta2) {
    __shared__ unsigned long long stage[3 * EB];   // 24 KB
    __shared__ int c512[512];                      // +2 KB
    __shared__ int offE[512];                      // +2 KB
    __shared__ int gb[512];                        // +2 KB
    int t = threadIdx.x;
    c512[t] = 0;
    __syncthreads();
    int base = blockIdx.x * EB;
    int nE = NNZ - base; if (nE > EB) nE = EB;
    int tot = 3 * nE;

    unsigned long long ent[6]; int sbA[6]; int loc[6];
#pragma unroll
    for (int k = 0; k < 2; ++k) {
        int i = k * 512 + t;
        int e = base + i;
        if (i < nE) {
            int r0 = __builtin_nontemporal_load(&fr[e]);
            unsigned p0 = pack_cv(__builtin_nontemporal_load(&fc[e]),
                                  __builtin_nontemporal_load(&fv[e]));
            int s0 = r0 / SUBW;
            ent[3*k]   = ((unsigned long long)s0 << 48)
                       | ((unsigned long long)(r0 - s0 * SUBW) << 32) | p0;
            sbA[3*k] = s0;  loc[3*k] = atomicAdd(&c512[s0], 1);

            int r1 = __builtin_nontemporal_load(&a1r[e]);
            unsigned p1 = pack_cv(__builtin_nontemporal_load(&a1c[e]),
                                  __builtin_nontemporal_load(&a1v[e]));
            int s1 = r1 / SUBW;
            ent[3*k+1] = ((unsigned long long)s1 << 48)
                       | ((unsigned long long)(SUBW + r1 - s1 * SUBW) << 32) | p1;
            sbA[3*k+1] = s1;  loc[3*k+1] = atomicAdd(&c512[s1], 1);

            int r2 = __builtin_nontemporal_load(&a2r[e]);
            unsigned p2 = pack_cv(__builtin_nontemporal_load(&a2c[e]),
                                  __builtin_nontemporal_load(&a2v[e]));
            int s2 = r2 / SUBW;
            ent[3*k+2] = ((unsigned long long)s2 << 48)
                       | ((unsigned long long)(2 * SUBW + r2 - s2 * SUBW) << 32) | p2;
            sbA[3*k+2] = s2;  loc[3*k+2] = atomicAdd(&c512[s2], 1);
        } else {
            sbA[3*k] = sbA[3*k+1] = sbA[3*k+2] = -1;
        }
    }
    __syncthreads();
    // Hillis-Steele inclusive scan over the 512 bucket counts.
    offE[t] = c512[t];
    __syncthreads();
    for (int off = 1; off < 512; off <<= 1) {
        int v = (t >= off) ? offE[t - off] : 0;
        __syncthreads();
        offE[t] += v;
        __syncthreads();
    }
    int excl = offE[t] - c512[t];
    __syncthreads();
    offE[t] = excl;
    if (c512[t] > 0) gb[t] = atomicAdd(&subcur[t], c512[t]);
    __syncthreads();
#pragma unroll
    for (int k = 0; k < 6; ++k) {
        if (sbA[k] >= 0) stage[offE[sbA[k]] + loc[k]] = ent[k];
    }
    __syncthreads();
    // Write-out: ~6-entry contiguous chunks per bucket.
    for (int i = t; i < tot; i += 512) {
        unsigned long long v = stage[i];
        int sb = (int)(v >> 48);
        int g = sb * SUBCAP + gb[sb] + (i - offE[sb]);
        gpack2[g] = (unsigned)v;
        gmeta2[g] = (unsigned short)(v >> 32);   // key in [0,294)
    }
}

// -----------------------------------------------------------------------------
// B (sort_write_feat_kernel): per-bucket LDS counting sort + FUSED feat phase.
// After the sort, the block holds ALL feat entries of its 98 rows in LDS:
//   - writes adj segs 1/2 to spack (contiguous, self-allocated via cur3) and
//     emits starts+rowlen;
//   - then 16 x 32-lane row-groups compute xw rows straight from LDS
//     (same-address broadcast reads replace __shfl; Wc is cache-resident).
// Deletes the separate feat_gather kernel and seg-0's 3.2 MB write + 3.2 MB
// re-read. xw therefore must NOT alias the bucket region (other blocks still
// read their buckets while we write xw) — xw is a separate allocation now.
// -----------------------------------------------------------------------------
__global__ __launch_bounds__(512) void sort_write_feat_kernel(
        const unsigned* __restrict__ gpack2,
        const unsigned short* __restrict__ gmeta2,
        const int* __restrict__ subcur,
        int* __restrict__ cur3,
        int* __restrict__ starts,
        int* __restrict__ rowlen,
        unsigned* __restrict__ spack,
        const uint4* __restrict__ Wc,
        ushort4* __restrict__ xw1s,
        ushort4* __restrict__ xw2s) {
    int sb = blockIdx.x;                 // 0..510
    int n = subcur[sb];
    __shared__ int h[512];
    __shared__ int e[512];
    __shared__ int cur[512];
    __shared__ int segbase[4];           // [0]=0 .. [3]=n
    __shared__ int gbs[3];               // per-segment global (within-seg) base
    __shared__ unsigned sorted[SUBCAP];  // 24 KB
    int t = threadIdx.x;
    h[t] = 0;
    __syncthreads();
    long base = (long)sb * SUBCAP;
    unsigned pk[12]; short ky[12];
#pragma unroll
    for (int k = 0; k < 12; ++k) {           // SUBCAP = 12*512 exactly
        int i = t + k * 512;
        if (i < n) {
            pk[k] = gpack2[base + i];
            ky[k] = (short)gmeta2[base + i]; // key in [0,294)
            atomicAdd(&h[ky[k]], 1);
        } else ky[k] = -1;
    }
    __syncthreads();
    e[t] = h[t];
    __syncthreads();
    for (int off = 1; off < 512; off <<= 1) {
        int v = (t >= off) ? e[t - off] : 0;
        __syncthreads();
        e[t] += v;
        __syncthreads();
    }
    int excl = e[t] - h[t];
    __syncthreads();
    e[t] = excl;
    cur[t] = excl;
    __syncthreads();
    if (t == 0) {
        segbase[0] = 0;
        segbase[1] = e[SUBW];
        segbase[2] = e[2 * SUBW];
        segbase[3] = n;
    }
    __syncthreads();
    if (t < 3) gbs[t] = atomicAdd(&cur3[t], segbase[t + 1] - segbase[t]);
    // LDS scatter (concurrent with the t<3 reservations; disjoint memory)
#pragma unroll
    for (int k = 0; k < 12; ++k) {
        if (ky[k] >= 0) {
            int pos = atomicAdd(&cur[ky[k]], 1);
            sorted[pos] = pk[k];
        }
    }
    __syncthreads();
    // Emit row pointers + lengths (98 rows x 3 segments; seg0 harmless/unused).
    if (t < 3 * SUBW) {
        int s = t / SUBW, d = t - s * SUBW;
        int r = sb * SUBW + d;
        if (r < N_NODES) {
            int gr = s * N_NODES + r;
            starts[gr] = s * NNZ + gbs[s] + (e[t] - segbase[s]);
            rowlen[gr] = h[t];
        }
    }
    // Coalesced contiguous entry write-out: adj segments 1/2 ONLY (seg0 —
    // the feat entries — are consumed in-LDS below, never written to spack).
    int s1 = segbase[1], s2 = segbase[2];
#pragma unroll
    for (int k = 0; k < 12; ++k) {
        int i = t + k * 512;
        if (i >= s1 && i < n) {
            int sg = (i < s2) ? 1 : 2;
            spack[sg * NNZ + gbs[sg] + (i - segbase[sg])] = sorted[i];
        }
    }
    // FUSED feat phase: 16 row-groups of 32 lanes; row keys 0..97 are seg0.
    // Lane l owns dims [4l..4l+4) of each table (via Wc interleave).
    int grp  = t >> 5;                   // 0..15
    int lane = t & 31;
    for (int rowIdx = grp; rowIdx < SUBW; rowIdx += 16) {
        int r = sb * SUBW + rowIdx;
        if (r >= N_NODES) continue;      // uniform per group
        int cnt = h[rowIdx];
        int bs  = e[rowIdx];
        float4 a1 = make_float4(0.f, 0.f, 0.f, 0.f);
        float4 a2 = make_float4(0.f, 0.f, 0.f, 0.f);
        int j = 0;
        for (; j + 3 < cnt; j += 4) {
            unsigned p0 = sorted[bs + j];        // LDS broadcast (no conflict)
            unsigned p1 = sorted[bs + j + 1];
            unsigned p2 = sorted[bs + j + 2];
            unsigned p3 = sorted[bs + j + 3];
            uint4 w0 = Wc[upk_c(p0) * 32 + lane];
            uint4 w1 = Wc[upk_c(p1) * 32 + lane];
            uint4 w2 = Wc[upk_c(p2) * 32 + lane];
            uint4 w3 = Wc[upk_c(p3) * 32 + lane];
            float v0 = upk_v(p0), v1 = upk_v(p1), v2 = upk_v(p2), v3 = upk_v(p3);
            a1.x += v0 * h2f((unsigned short)(w0.x & 0xffffu));
            a1.y += v0 * h2f((unsigned short)(w0.x >> 16));
            a1.z += v0 * h2f((unsigned short)(w0.y & 0xffffu));
            a1.w += v0 * h2f((unsigned short)(w0.y >> 16));
            a2.x += v0 * h2f((unsigned short)(w0.z & 0xffffu));
            a2.y += v0 * h2f((unsigned short)(w0.z >> 16));
            a2.z += v0 * h2f((unsigned short)(w0.w & 0xffffu));
            a2.w += v0 * h2f((unsigned short)(w0.w >> 16));
            a1.x += v1 * h2f((unsigned short)(w1.x & 0xffffu));
            a1.y += v1 * h2f((unsigned short)(w1.x >> 16));
            a1.z += v1 * h2f((unsigned short)(w1.y & 0xffffu));
            a1.w += v1 * h2f((unsigned short)(w1.y >> 16));
            a2.x += v1 * h2f((unsigned short)(w1.z & 0xffffu));
            a2.y += v1 * h2f((unsigned short)(w1.z >> 16));
            a2.z += v1 * h2f((unsigned short)(w1.w & 0xffffu));
            a2.w += v1 * h2f((unsigned short)(w1.w >> 16));
            a1.x += v2 * h2f((unsigned short)(w2.x & 0xffffu));
            a1.y += v2 * h2f((unsigned short)(w2.x >> 16));
            a1.z += v2 * h2f((unsigned short)(w2.y & 0xffffu));
            a1.w += v2 * h2f((unsigned short)(w2.y >> 16));
            a2.x += v2 * h2f((unsigned short)(w2.z & 0xffffu));
            a2.y += v2 * h2f((unsigned short)(w2.z >> 16));
            a2.z += v2 * h2f((unsigned short)(w2.w & 0xffffu));
            a2.w += v2 * h2f((unsigned short)(w2.w >> 16));
            a1.x += v3 * h2f((unsigned short)(w3.x & 0xffffu));
            a1.y += v3 * h2f((unsigned short)(w3.x >> 16));
            a1.z += v3 * h2f((unsigned short)(w3.y & 0xffffu));
            a1.w += v3 * h2f((unsigned short)(w3.y >> 16));
            a2.x += v3 * h2f((unsigned short)(w3.z & 0xffffu));
            a2.y += v3 * h2f((unsigned short)(w3.z >> 16));
            a2.z += v3 * h2f((unsigned short)(w3.w & 0xffffu));
            a2.w += v3 * h2f((unsigned short)(w3.w >> 16));
        }
        for (; j < cnt; ++j) {
            unsigned p = sorted[bs + j];
            float v = upk_v(p);
            uint4 w = Wc[upk_c(p) * 32 + lane];
            a1.x += v * h2f((unsigned short)(w.x & 0xffffu));
            a1.y += v * h2f((unsigned short)(w.x >> 16));
            a1.z += v * h2f((unsigned short)(w.y & 0xffffu));
            a1.w += v * h2f((unsigned short)(w.y >> 16));
            a2.x += v * h2f((unsigned short)(w.z & 0xffffu));
            a2.y += v * h2f((unsigned short)(w.z >> 16));
            a2.z += v * h2f((unsigned short)(w.w & 0xffffu));
            a2.w += v * h2f((unsigned short)(w.w >> 16));
        }
        ushort4 q1, q2;
        q1.x = __half_as_ushort(__float2half(a1.x));
        q1.y = __half_as_ushort(__float2half(a1.y));
        q1.z = __half_as_ushort(__float2half(a1.z));
        q1.w = __half_as_ushort(__float2half(a1.w));
        q2.x = __half_as_ushort(__float2half(a2.x));
        q2.y = __half_as_ushort(__float2half(a2.y));
        q2.z = __half_as_ushort(__float2half(a2.z));
        q2.w = __half_as_ushort(__float2half(a2.w));
        // 32-dim-slice layout: xw[s][r][d32], lane's slice = lane>>3.
        size_t idx = (size_t)(lane >> 3) * (N_NODES * 8) + (size_t)r * 8 + (lane & 7);
        xw1s[idx] = q1;
        xw2s[idx] = q2;
    }
}

// -----------------------------------------------------------------------------
// Phase 2, FUSED (round-15/16 measured ~62 us; latency-floor, keep):
//   out[r, 32s:32s+32] = relu( sum_adj1 v*xw1[s][c][:] + sum_adj2 v*xw2[s][c][:] )
// -----------------------------------------------------------------------------
__global__ __launch_bounds__(512) void adj_pass_fused(
        const int* __restrict__ starts,
        const int* __restrict__ rowlen,
        const unsigned* __restrict__ spack,
        const ushort4* __restrict__ xw1s,
        const ushort4* __restrict__ xw2s,
        vf4* __restrict__ out) {
    int s  = blockIdx.x & (ADJ_SL - 1);
    int rc = blockIdx.x >> 2;
    int g  = threadIdx.x >> 3;          // 64 row-groups per block
    int q  = threadIdx.x & 7;
    int r  = rc * 64 + g;
    bool valid = (r < N_NODES);
    vf4 acc = {0.f, 0.f, 0.f, 0.f};

#pragma unroll
    for (int rel = 0; rel < 2; ++rel) {
        const ushort4* __restrict__ sl =
            ((rel == 0) ? xw1s : xw2s) + (size_t)s * (N_NODES * 8);
        int st = 0, en = 0;
        if (valid) {
            st = starts[(1 + rel) * N_NODES + r];
            en = st + rowlen[(1 + rel) * N_NODES + r];
        }
        for (int base = st; base < en; base += 16) {
            int m = en - base;
            unsigned pk0 = (q < m)     ? spack[base + q]     : 0u;
            unsigned pk1 = (8 + q < m) ? spack[base + 8 + q] : 0u;
            {
                unsigned pp[8]; ushort4 xx[8];
#pragma unroll
                for (int k = 0; k < 8; ++k) pp[k] = __shfl(pk0, k, 8);
#pragma unroll
                for (int k = 0; k < 8; ++k) xx[k] = sl[upk_c(pp[k]) * 8 + q];
#pragma unroll
                for (int k = 0; k < 8; ++k) {
                    float v = upk_v(pp[k]);
                    acc.x += v * h2f(xx[k].x); acc.y += v * h2f(xx[k].y);
                    acc.z += v * h2f(xx[k].z); acc.w += v * h2f(xx[k].w);
                }
            }
            if (m <= 8) continue;
            {
                unsigned pp[8]; ushort4 xx[8];
#pragma unroll
                for (int k = 0; k < 8; ++k) pp[k] = __shfl(pk1, k, 8);
#pragma unroll
                for (int k = 0; k < 8; ++k) xx[k] = sl[upk_c(pp[k]) * 8 + q];
#pragma unroll
                for (int k = 0; k < 8; ++k) {
                    float v = upk_v(pp[k]);
                    acc.x += v * h2f(xx[k].x); acc.y += v * h2f(xx[k].y);
                    acc.z += v * h2f(xx[k].z); acc.w += v * h2f(xx[k].w);
                }
            }
        }
    }
    if (valid) {
        vf4 res;
        res.x = fmaxf(acc.x, 0.f);
        res.y = fmaxf(acc.y, 0.f);
        res.z = fmaxf(acc.z, 0.f);
        res.w = fmaxf(acc.w, 0.f);
        __builtin_nontemporal_store(res, &out[(size_t)r * 32 + s * 8 + q]);
    }
}

extern "C" void kernel_launch(void* const* d_in, const int* in_sizes, int n_in,
                              void* d_out, int out_size, void* d_ws, size_t ws_size,
                              hipStream_t stream) {
    const int*   feat_row  = (const int*)  d_in[0];
    const int*   feat_col  = (const int*)  d_in[1];
    const float* feat_vals = (const float*)d_in[2];
    const int*   adj1_row  = (const int*)  d_in[3];
    const int*   adj1_col  = (const int*)  d_in[4];
    const float* adj1_vals = (const float*)d_in[5];
    const int*   adj2_row  = (const int*)  d_in[6];
    const int*   adj2_col  = (const int*)  d_in[7];
    const float* adj2_vals = (const float*)d_in[8];
    const float* W1        = (const float*)d_in[9];
    const float* W2        = (const float*)d_in[10];

    // Workspace layout (~56 MB, NO aliasing: the fused kernel writes xw while
    // other blocks still read their buckets).
    char* ws = (char*)d_ws;
    unsigned* spack = (unsigned*)ws;            ws += (size_t)TOTAL_NNZ * 4;          // 9.6 MB
    int*      starts= (int*)ws;                 ws += (size_t)SCAN_N * 4;             // 600 KB
    int*      rowlen= (int*)ws;                 ws += (size_t)SCAN_N * 4;             // 600 KB
    int*      subcur= (int*)ws;                 ws += 512 * 4;                        // 511 used
    int*      cur3  = (int*)ws;                 ws += 16 * 4;                         // 3 used
    uint4*    Wc    = (uint4*)ws;               ws += (size_t)256 * 32 * 16;          // 128 KB
    unsigned* gpack2 = (unsigned*)ws;           ws += (size_t)NSB * SUBCAP * 4;       // 12.6 MB
    unsigned short* gmeta2 = (unsigned short*)ws; ws += (size_t)NSB * SUBCAP * 2;     // 6.3 MB
    ushort4*  xw1s  = (ushort4*)ws;             ws += (size_t)N_NODES * OUT_DIM * 2;  // 12.8 MB
    ushort4*  xw2s  = (ushort4*)ws;             ws += (size_t)N_NODES * OUT_DIM * 2;  // 12.8 MB

    // Zero cursors: subcur(512) + cur3(16), contiguous.
    (void)hipMemsetAsync(subcur, 0, (512 + 16) * sizeof(int), stream);

    // W prep: interleaved fp16 table.
    wprep_kernel<<<32, 256, 0, stream>>>(W1, W2, Wc);

    // A: single pass — read all 9 streams once, bucket into 511 sub-buckets.
    superbucket_kernel<<<SB_GRID, 512, 0, stream>>>(
        feat_row, feat_col, feat_vals,
        adj1_row, adj1_col, adj1_vals,
        adj2_row, adj2_col, adj2_vals,
        subcur, gpack2, gmeta2);

    // B: sort + adj spack write + FUSED feat xw compute.
    sort_write_feat_kernel<<<NSB, 512, 0, stream>>>(
        gpack2, gmeta2, subcur, cur3, starts, rowlen, spack, Wc, xw1s, xw2s);

    // Phase 2: FUSED rel0+rel1, 32-dim slices.
    adj_pass_fused<<<ADJ_SL * ADJ_RC, 512, 0, stream>>>(
        starts, rowlen, spack, xw1s, xw2s, (vf4*)d_out);
}

// Round 19
// 212.909 us; speedup vs baseline: 1.4775x; 1.0295x over previous
//
#include <hip/hip_runtime.h>
#include <hip/hip_fp16.h>

// Problem constants (fixed by the reference setup)
#define N_NODES 50000
#define IN_DIM 256
#define OUT_DIM 128
#define NNZ 800000          // nnz for feat, adj1, adj2 each
#define SCAN_N (3 * N_NODES)        // 150000 row pointers (feat | adj1 | adj2)
#define TOTAL_NNZ (3 * NNZ)         // spack sized for 3 segs; seg0 unused

// Sub-buckets: 98-row ranges, 511 of them (511*98 = 50078 >= 50000).
// Expected entries/bucket = 2.4M*98/50000 = 4704, sigma ~68.
// SUBCAP 6144 = mean + 21 sigma (populations HW-validated rounds 2..17).
#define NSB 511
#define SUBW 98
#define SUBCAP 6144

// superbucket: 512 threads, 1024 edges/block -> 3072 entries staged in 24 KB.
#define EB 1024
#define SB_GRID ((NNZ + EB - 1) / EB)   // 782

// adj phase: ONE fused dispatch (measured ~62 us across rounds 15-17,
// request/latency floor; keep).
#define ADJ_SL 4
#define ADJ_RC ((N_NODES + 63) / 64)  // 782 row-chunks of 64 rows

// Native clang vector types.
typedef float vf4 __attribute__((ext_vector_type(4)));

// Packed entry: [col:16 | fp16(val):16].  adj cols < 50000 < 65536, feat cols < 256.
static __device__ __forceinline__ unsigned pack_cv(int c, float v) {
    return ((unsigned)c << 16) | (unsigned)__half_as_ushort(__float2half(v));
}
static __device__ __forceinline__ int   upk_c(unsigned pk) { return (int)(pk >> 16); }
static __device__ __forceinline__ float upk_v(unsigned pk) {
    return __half2float(__ushort_as_half((unsigned short)(pk & 0xffffu)));
}
static __device__ __forceinline__ float h2f(unsigned short h) {
    return __half2float(__ushort_as_half(h));
}
static __device__ __forceinline__ unsigned pk2h(float x, float y) {
    return (unsigned)__half_as_ushort(__float2half(x))
         | ((unsigned)__half_as_ushort(__float2half(y)) << 16);
}

// -----------------------------------------------------------------------------
// wprep: interleave W1|W2 into ONE fp16 table (cache-resident, 128 KB).
// Wc[c*32 + l] (uint4) = { w1[c, 4l..4l+3], w2[c, 4l..4l+3] } as 8 halves.
// -----------------------------------------------------------------------------
__global__ void wprep_kernel(const float* __restrict__ W1,
                             const float* __restrict__ W2,
                             uint4* __restrict__ Wc) {
    int idx = blockIdx.x * 256 + threadIdx.x;   // 8192 = 256 rows * 32 lanes
    const float4* w1 = (const float4*)W1;
    const float4* w2 = (const float4*)W2;
    float4 a = w1[idx];
    float4 b = w2[idx];
    uint4 o;
    o.x = pk2h(a.x, a.y);
    o.y = pk2h(a.z, a.w);
    o.z = pk2h(b.x, b.y);
    o.w = pk2h(b.z, b.w);
    Wc[idx] = o;
}

// -----------------------------------------------------------------------------
// A (superbucket_kernel): read every edge ONCE, LDS-group 3072 entries by final
// 98-row bucket (row/98, 511 buckets), append ~6-entry chunks to per-bucket
// storage. Entry = u64 [sb:16|key:16|pack:32], key = seg*98 + row%98 in [0,294).
// Wave-level scan (18 barriers -> 3) + single u64 store per entry.
// -----------------------------------------------------------------------------
__global__ __launch_bounds__(512) void superbucket_kernel(
        const int* __restrict__ fr, const int* __restrict__ fc,
        const float* __restrict__ fv,
        const int* __restrict__ a1r, const int* __restrict__ a1c,
        const float* __restrict__ a1v,
        const int* __restrict__ a2r, const int* __restrict__ a2c,
        const float* __restrict__ a2v,
        int* __restrict__ subcur,
        unsigned long long* __restrict__ gbuf) {
    __shared__ unsigned long long stage[3 * EB];   // 24 KB
    __shared__ int c512[512];                      // +2 KB
    __shared__ int offE[512];                      // +2 KB
    __shared__ int gb[512];                        // +2 KB
    __shared__ int wsum[8];
    int t = threadIdx.x;
    c512[t] = 0;
    __syncthreads();
    int base = blockIdx.x * EB;
    int nE = NNZ - base; if (nE > EB) nE = EB;
    int tot = 3 * nE;

    unsigned long long ent[6]; int sbA[6]; int loc[6];
#pragma unroll
    for (int k = 0; k < 2; ++k) {
        int i = k * 512 + t;
        int e = base + i;
        if (i < nE) {
            int r0 = __builtin_nontemporal_load(&fr[e]);
            unsigned p0 = pack_cv(__builtin_nontemporal_load(&fc[e]),
                                  __builtin_nontemporal_load(&fv[e]));
            int s0 = r0 / SUBW;
            ent[3*k]   = ((unsigned long long)s0 << 48)
                       | ((unsigned long long)(r0 - s0 * SUBW) << 32) | p0;
            sbA[3*k] = s0;  loc[3*k] = atomicAdd(&c512[s0], 1);

            int r1 = __builtin_nontemporal_load(&a1r[e]);
            unsigned p1 = pack_cv(__builtin_nontemporal_load(&a1c[e]),
                                  __builtin_nontemporal_load(&a1v[e]));
            int s1 = r1 / SUBW;
            ent[3*k+1] = ((unsigned long long)s1 << 48)
                       | ((unsigned long long)(SUBW + r1 - s1 * SUBW) << 32) | p1;
            sbA[3*k+1] = s1;  loc[3*k+1] = atomicAdd(&c512[s1], 1);

            int r2 = __builtin_nontemporal_load(&a2r[e]);
            unsigned p2 = pack_cv(__builtin_nontemporal_load(&a2c[e]),
                                  __builtin_nontemporal_load(&a2v[e]));
            int s2 = r2 / SUBW;
            ent[3*k+2] = ((unsigned long long)s2 << 48)
                       | ((unsigned long long)(2 * SUBW + r2 - s2 * SUBW) << 32) | p2;
            sbA[3*k+2] = s2;  loc[3*k+2] = atomicAdd(&c512[s2], 1);
        } else {
            sbA[3*k] = sbA[3*k+1] = sbA[3*k+2] = -1;
        }
    }
    __syncthreads();
    // Wave-level inclusive scan over the 512 bucket counts (2 barriers).
    int lane = t & 63, wid = t >> 6;
    int v = c512[t];
    int incl = v;
#pragma unroll
    for (int d = 1; d < 64; d <<= 1) {
        int u = __shfl_up(incl, d, 64);
        if (lane >= d) incl += u;
    }
    if (lane == 63) wsum[wid] = incl;
    __syncthreads();
    int wpre = 0;
#pragma unroll
    for (int w = 0; w < 8; ++w) wpre += (w < wid) ? wsum[w] : 0;
    int excl = incl + wpre - v;
    offE[t] = excl;
    gb[t] = (v > 0) ? atomicAdd(&subcur[t], v) : 0;
    __syncthreads();
#pragma unroll
    for (int k = 0; k < 6; ++k) {
        if (sbA[k] >= 0) stage[offE[sbA[k]] + loc[k]] = ent[k];
    }
    __syncthreads();
    // Write-out: ~6-entry contiguous chunks per bucket, single u64 store.
    for (int i = t; i < tot; i += 512) {
        unsigned long long e = stage[i];
        int sb = (int)(e >> 48);
        gbuf[(size_t)sb * SUBCAP + gb[sb] + (i - offE[sb])] = e;
    }
}

// -----------------------------------------------------------------------------
// B (sort_write_feat_kernel): per-bucket LDS counting sort + FUSED feat phase.
//   - writes adj segs 1/2 to spack (contiguous, self-allocated via cur3) and
//     emits starts+rowlen;
//   - 16 x 32-lane row-groups compute xw rows straight from LDS (broadcast
//     reads; Wc cache-resident). Wave-level scan; single u64 load per entry.
// -----------------------------------------------------------------------------
__global__ __launch_bounds__(512) void sort_write_feat_kernel(
        const unsigned long long* __restrict__ gbuf,
        const int* __restrict__ subcur,
        int* __restrict__ cur3,
        int* __restrict__ starts,
        int* __restrict__ rowlen,
        unsigned* __restrict__ spack,
        const uint4* __restrict__ Wc,
        ushort4* __restrict__ xw1s,
        ushort4* __restrict__ xw2s) {
    int sb = blockIdx.x;                 // 0..510
    int n = subcur[sb];
    __shared__ int h[512];
    __shared__ int e[512];
    __shared__ int cur[512];
    __shared__ int gbs[3];               // per-segment global (within-seg) base
    __shared__ int wsum[8];
    __shared__ unsigned sorted[SUBCAP];  // 24 KB
    int t = threadIdx.x;
    h[t] = 0;
    __syncthreads();
    size_t base = (size_t)sb * SUBCAP;
    unsigned pk[12]; short ky[12];
#pragma unroll
    for (int k = 0; k < 12; ++k) {           // SUBCAP = 12*512 exactly
        int i = t + k * 512;
        if (i < n) {
            unsigned long long ent = gbuf[base + i];
            pk[k] = (unsigned)ent;
            ky[k] = (short)((ent >> 32) & 0xffffu);  // key in [0,294)
            atomicAdd(&h[ky[k]], 1);
        } else ky[k] = -1;
    }
    __syncthreads();
    // Wave-level inclusive scan over h[512] (2 barriers).
    int lane = t & 63, wid = t >> 6;
    int v = h[t];
    int incl = v;
#pragma unroll
    for (int d = 1; d < 64; d <<= 1) {
        int u = __shfl_up(incl, d, 64);
        if (lane >= d) incl += u;
    }
    if (lane == 63) wsum[wid] = incl;
    __syncthreads();
    int wpre = 0;
#pragma unroll
    for (int w = 0; w < 8; ++w) wpre += (w < wid) ? wsum[w] : 0;
    int excl = incl + wpre - v;
    e[t] = excl;
    cur[t] = excl;
    __syncthreads();
    // Reserve per-segment global ranges from the scanned boundaries.
    if (t < 3) {
        int lo = (t == 0) ? 0 : ((t == 1) ? e[SUBW] : e[2 * SUBW]);
        int hi = (t == 0) ? e[SUBW] : ((t == 1) ? e[2 * SUBW] : n);
        gbs[t] = atomicAdd(&cur3[t], hi - lo);
    }
    // LDS scatter (concurrent with the t<3 reservations; disjoint memory).
#pragma unroll
    for (int k = 0; k < 12; ++k) {
        if (ky[k] >= 0) {
            int pos = atomicAdd(&cur[ky[k]], 1);
            sorted[pos] = pk[k];
        }
    }
    __syncthreads();
    int s1 = e[SUBW];                    // local start of adj1 entries
    int s2 = e[2 * SUBW];                // local start of adj2 entries
    // Emit row pointers + lengths (98 rows x 3 segments; seg0 harmless/unused).
    if (t < 3 * SUBW) {
        int s = t / SUBW, d = t - s * SUBW;
        int r = sb * SUBW + d;
        if (r < N_NODES) {
            int segb = (s == 0) ? 0 : ((s == 1) ? s1 : s2);
            int gr = s * N_NODES + r;
            starts[gr] = s * NNZ + gbs[s] + (e[t] - segb);
            rowlen[gr] = h[t];
        }
    }
    // Coalesced contiguous entry write-out: adj segments 1/2 ONLY.
#pragma unroll
    for (int k = 0; k < 12; ++k) {
        int i = t + k * 512;
        if (i >= s1 && i < n) {
            int sg = (i < s2) ? 1 : 2;
            int segb = (i < s2) ? s1 : s2;
            spack[sg * NNZ + gbs[sg] + (i - segb)] = sorted[i];
        }
    }
    // FUSED feat phase: 16 row-groups of 32 lanes; row keys 0..97 are seg0.
    int grp  = t >> 5;                   // 0..15
    int ln   = t & 31;
    for (int rowIdx = grp; rowIdx < SUBW; rowIdx += 16) {
        int r = sb * SUBW + rowIdx;
        if (r >= N_NODES) continue;      // uniform per group
        int cnt = h[rowIdx];
        int bs  = e[rowIdx];
        float4 a1 = make_float4(0.f, 0.f, 0.f, 0.f);
        float4 a2 = make_float4(0.f, 0.f, 0.f, 0.f);
        int j = 0;
        for (; j + 3 < cnt; j += 4) {
            unsigned p0 = sorted[bs + j];        // LDS broadcast (no conflict)
            unsigned p1 = sorted[bs + j + 1];
            unsigned p2 = sorted[bs + j + 2];
            unsigned p3 = sorted[bs + j + 3];
            uint4 w0 = Wc[upk_c(p0) * 32 + ln];
            uint4 w1 = Wc[upk_c(p1) * 32 + ln];
            uint4 w2 = Wc[upk_c(p2) * 32 + ln];
            uint4 w3 = Wc[upk_c(p3) * 32 + ln];
            float v0 = upk_v(p0), v1 = upk_v(p1), v2 = upk_v(p2), v3 = upk_v(p3);
            a1.x += v0 * h2f((unsigned short)(w0.x & 0xffffu));
            a1.y += v0 * h2f((unsigned short)(w0.x >> 16));
            a1.z += v0 * h2f((unsigned short)(w0.y & 0xffffu));
            a1.w += v0 * h2f((unsigned short)(w0.y >> 16));
            a2.x += v0 * h2f((unsigned short)(w0.z & 0xffffu));
            a2.y += v0 * h2f((unsigned short)(w0.z >> 16));
            a2.z += v0 * h2f((unsigned short)(w0.w & 0xffffu));
            a2.w += v0 * h2f((unsigned short)(w0.w >> 16));
            a1.x += v1 * h2f((unsigned short)(w1.x & 0xffffu));
            a1.y += v1 * h2f((unsigned short)(w1.x >> 16));
            a1.z += v1 * h2f((unsigned short)(w1.y & 0xffffu));
            a1.w += v1 * h2f((unsigned short)(w1.y >> 16));
            a2.x += v1 * h2f((unsigned short)(w1.z & 0xffffu));
            a2.y += v1 * h2f((unsigned short)(w1.z >> 16));
            a2.z += v1 * h2f((unsigned short)(w1.w & 0xffffu));
            a2.w += v1 * h2f((unsigned short)(w1.w >> 16));
            a1.x += v2 * h2f((unsigned short)(w2.x & 0xffffu));
            a1.y += v2 * h2f((unsigned short)(w2.x >> 16));
            a1.z += v2 * h2f((unsigned short)(w2.y & 0xffffu));
            a1.w += v2 * h2f((unsigned short)(w2.y >> 16));
            a2.x += v2 * h2f((unsigned short)(w2.z & 0xffffu));
            a2.y += v2 * h2f((unsigned short)(w2.z >> 16));
            a2.z += v2 * h2f((unsigned short)(w2.w & 0xffffu));
            a2.w += v2 * h2f((unsigned short)(w2.w >> 16));
            a1.x += v3 * h2f((unsigned short)(w3.x & 0xffffu));
            a1.y += v3 * h2f((unsigned short)(w3.x >> 16));
            a1.z += v3 * h2f((unsigned short)(w3.y & 0xffffu));
            a1.w += v3 * h2f((unsigned short)(w3.y >> 16));
            a2.x += v3 * h2f((unsigned short)(w3.z & 0xffffu));
            a2.y += v3 * h2f((unsigned short)(w3.z >> 16));
            a2.z += v3 * h2f((unsigned short)(w3.w & 0xffffu));
            a2.w += v3 * h2f((unsigned short)(w3.w >> 16));
        }
        for (; j < cnt; ++j) {
            unsigned p = sorted[bs + j];
            float v5 = upk_v(p);
            uint4 w = Wc[upk_c(p) * 32 + ln];
            a1.x += v5 * h2f((unsigned short)(w.x & 0xffffu));
            a1.y += v5 * h2f((unsigned short)(w.x >> 16));
            a1.z += v5 * h2f((unsigned short)(w.y & 0xffffu));
            a1.w += v5 * h2f((unsigned short)(w.y >> 16));
            a2.x += v5 * h2f((unsigned short)(w.z & 0xffffu));
            a2.y += v5 * h2f((unsigned short)(w.z >> 16));
            a2.z += v5 * h2f((unsigned short)(w.w & 0xffffu));
            a2.w += v5 * h2f((unsigned short)(w.w >> 16));
        }
        ushort4 q1, q2;
        q1.x = __half_as_ushort(__float2half(a1.x));
        q1.y = __half_as_ushort(__float2half(a1.y));
        q1.z = __half_as_ushort(__float2half(a1.z));
        q1.w = __half_as_ushort(__float2half(a1.w));
        q2.x = __half_as_ushort(__float2half(a2.x));
        q2.y = __half_as_ushort(__float2half(a2.y));
        q2.z = __half_as_ushort(__float2half(a2.z));
        q2.w = __half_as_ushort(__float2half(a2.w));
        // 32-dim-slice layout: xw[s][r][d32], lane's slice = ln>>3.
        size_t idx = (size_t)(ln >> 3) * (N_NODES * 8) + (size_t)r * 8 + (ln & 7);
        xw1s[idx] = q1;
        xw2s[idx] = q2;
    }
}

// -----------------------------------------------------------------------------
// Phase 2, FUSED (measured ~62 us rounds 15-17; request/latency floor, keep):
//   out[r, 32s:32s+32] = relu( sum_adj1 v*xw1[s][c][:] + sum_adj2 v*xw2[s][c][:] )
// -----------------------------------------------------------------------------
__global__ __launch_bounds__(512) void adj_pass_fused(
        const int* __restrict__ starts,
        const int* __restrict__ rowlen,
        const unsigned* __restrict__ spack,
        const ushort4* __restrict__ xw1s,
        const ushort4* __restrict__ xw2s,
        vf4* __restrict__ out) {
    int s  = blockIdx.x & (ADJ_SL - 1);
    int rc = blockIdx.x >> 2;
    int g  = threadIdx.x >> 3;          // 64 row-groups per block
    int q  = threadIdx.x & 7;
    int r  = rc * 64 + g;
    bool valid = (r < N_NODES);
    vf4 acc = {0.f, 0.f, 0.f, 0.f};

#pragma unroll
    for (int rel = 0; rel < 2; ++rel) {
        const ushort4* __restrict__ sl =
            ((rel == 0) ? xw1s : xw2s) + (size_t)s * (N_NODES * 8);
        int st = 0, en = 0;
        if (valid) {
            st = starts[(1 + rel) * N_NODES + r];
            en = st + rowlen[(1 + rel) * N_NODES + r];
        }
        for (int base = st; base < en; base += 16) {
            int m = en - base;
            unsigned pk0 = (q < m)     ? spack[base + q]     : 0u;
            unsigned pk1 = (8 + q < m) ? spack[base + 8 + q] : 0u;
            {
                unsigned pp[8]; ushort4 xx[8];
#pragma unroll
                for (int k = 0; k < 8; ++k) pp[k] = __shfl(pk0, k, 8);
#pragma unroll
                for (int k = 0; k < 8; ++k) xx[k] = sl[upk_c(pp[k]) * 8 + q];
#pragma unroll
                for (int k = 0; k < 8; ++k) {
                    float v = upk_v(pp[k]);
                    acc.x += v * h2f(xx[k].x); acc.y += v * h2f(xx[k].y);
                    acc.z += v * h2f(xx[k].z); acc.w += v * h2f(xx[k].w);
                }
            }
            if (m <= 8) continue;
            {
                unsigned pp[8]; ushort4 xx[8];
#pragma unroll
                for (int k = 0; k < 8; ++k) pp[k] = __shfl(pk1, k, 8);
#pragma unroll
                for (int k = 0; k < 8; ++k) xx[k] = sl[upk_c(pp[k]) * 8 + q];
#pragma unroll
                for (int k = 0; k < 8; ++k) {
                    float v = upk_v(pp[k]);
                    acc.x += v * h2f(xx[k].x); acc.y += v * h2f(xx[k].y);
                    acc.z += v * h2f(xx[k].z); acc.w += v * h2f(xx[k].w);
                }
            }
        }
    }
    if (valid) {
        vf4 res;
        res.x = fmaxf(acc.x, 0.f);
        res.y = fmaxf(acc.y, 0.f);
        res.z = fmaxf(acc.z, 0.f);
        res.w = fmaxf(acc.w, 0.f);
        __builtin_nontemporal_store(res, &out[(size_t)r * 32 + s * 8 + q]);
    }
}

extern "C" void kernel_launch(void* const* d_in, const int* in_sizes, int n_in,
                              void* d_out, int out_size, void* d_ws, size_t ws_size,
                              hipStream_t stream) {
    const int*   feat_row  = (const int*)  d_in[0];
    const int*   feat_col  = (const int*)  d_in[1];
    const float* feat_vals = (const float*)d_in[2];
    const int*   adj1_row  = (const int*)  d_in[3];
    const int*   adj1_col  = (const int*)  d_in[4];
    const float* adj1_vals = (const float*)d_in[5];
    const int*   adj2_row  = (const int*)  d_in[6];
    const int*   adj2_col  = (const int*)  d_in[7];
    const float* adj2_vals = (const float*)d_in[8];
    const float* W1        = (const float*)d_in[9];
    const float* W2        = (const float*)d_in[10];

    // Workspace layout (~62 MB, no aliasing).
    char* ws = (char*)d_ws;
    unsigned* spack = (unsigned*)ws;            ws += (size_t)TOTAL_NNZ * 4;          // 9.6 MB
    int*      starts= (int*)ws;                 ws += (size_t)SCAN_N * 4;             // 600 KB
    int*      rowlen= (int*)ws;                 ws += (size_t)SCAN_N * 4;             // 600 KB
    int*      subcur= (int*)ws;                 ws += 512 * 4;                        // 511 used
    int*      cur3  = (int*)ws;                 ws += 16 * 4;                         // 3 used
    uint4*    Wc    = (uint4*)ws;               ws += (size_t)256 * 32 * 16;          // 128 KB
    unsigned long long* gbuf = (unsigned long long*)ws;
    ws += (size_t)NSB * SUBCAP * 8;                                                  // 25.1 MB
    ushort4*  xw1s  = (ushort4*)ws;             ws += (size_t)N_NODES * OUT_DIM * 2;  // 12.8 MB
    ushort4*  xw2s  = (ushort4*)ws;             ws += (size_t)N_NODES * OUT_DIM * 2;  // 12.8 MB

    // Zero cursors: subcur(512) + cur3(16), contiguous.
    (void)hipMemsetAsync(subcur, 0, (512 + 16) * sizeof(int), stream);

    // W prep: interleaved fp16 table.
    wprep_kernel<<<32, 256, 0, stream>>>(W1, W2, Wc);

    // A: single pass — read all 9 streams once, bucket into 511 sub-buckets.
    superbucket_kernel<<<SB_GRID, 512, 0, stream>>>(
        feat_row, feat_col, feat_vals,
        adj1_row, adj1_col, adj1_vals,
        adj2_row, adj2_col, adj2_vals,
        subcur, gbuf);

    // B: sort + adj spack write + FUSED feat xw compute.
    sort_write_feat_kernel<<<NSB, 512, 0, stream>>>(
        gbuf, subcur, cur3, starts, rowlen, spack, Wc, xw1s, xw2s);

    // Phase 2: FUSED rel0+rel1, 32-dim slices.
    adj_pass_fused<<<ADJ_SL * ADJ_RC, 512, 0, stream>>>(
        starts, rowlen, spack, xw1s, xw2s, (vf4*)d_out);
}